// Round 6
// baseline (1916.246 us; speedup 1.0000x reference)
//
#include <hip/hip_runtime.h>
#include <hip/hip_bf16.h>

typedef _Float16 half8 __attribute__((ext_vector_type(8)));
typedef float floatx4 __attribute__((ext_vector_type(4)));

#define MFMA_F16(a, b, c) __builtin_amdgcn_mfma_f32_16x16x32_f16((a), (b), (c), 0, 0, 0)

// ---------------------------------------------------------------------------
// fused prep: 11 f32->f16 (optional transpose, scale) jobs in one launch.
// ---------------------------------------------------------------------------
struct PrepJobs {
  const float* src[11];
  _Float16* dst[11];
  int In[11], Out[11], elems[11], doT[11];
  float scale[11];
};

__global__ void prep_all_kernel(PrepJobs J) {
  int j = blockIdx.y;
  int idx = blockIdx.x * 256 + threadIdx.x;
  if (idx >= J.elems[j]) return;
  float v;
  if (J.doT[j]) { int o = idx / J.In[j], i = idx - o * J.In[j]; v = J.src[j][i * J.Out[j] + o]; }
  else          { v = J.src[j][idx]; }
  J.dst[j][idx] = (_Float16)(v * J.scale[j]);
}

// W~T[s][i] = kscale * sum_o Wk[i][o] * Wq[s][o]   (folds Wq into the k GEMM)
__global__ void prep_wtilde_kernel(const float* __restrict__ Wk, const float* __restrict__ Wq,
                                   _Float16* __restrict__ WT, float scale) {
  int idx = blockIdx.x * 256 + threadIdx.x;   // 32768 = 128 s * 256 i
  int s = idx >> 8, i = idx & 255;
  const float* wk = Wk + (size_t)i * 128;
  const float* wq = Wq + (size_t)s * 128;
  float acc = 0.f;
  #pragma unroll 4
  for (int o = 0; o < 128; o++) acc += wk[o] * wq[o];
  WT[idx] = (_Float16)(acc * scale);
}

// ---------------------------------------------------------------------------
// phase 1: fused LN + dual GEMM.  grid (1536, 2), 256 threads. (unchanged)
// ---------------------------------------------------------------------------
__global__ __launch_bounds__(256) void gemm_kv_kernel(
    const float* __restrict__ x, const float* __restrict__ lnw_g,
    const float* __restrict__ lnb_g, const _Float16* __restrict__ WT,
    _Float16* __restrict__ kout, _Float16* __restrict__ vTout) {
  __shared__ union {
    struct { _Float16 A[128][72]; _Float16 B[128][72]; } s;
    _Float16 C[128][136];
  } u;
  __shared__ float s_mean[128], s_rstd[128], s_red[256][2], s_lnw[256], s_lnb[256];

  const int tid = threadIdx.x;
  const int bx = blockIdx.x, y = blockIdx.y;
  const size_t r0 = (size_t)bx * 128;
  const int w = tid >> 6, lane = tid & 63, quad = lane >> 4, l15 = lane & 15;

  s_lnw[tid] = lnw_g[tid];
  s_lnb[tid] = lnb_g[tid];
  {
    int row = tid >> 1, half = tid & 1;
    const float* p = x + (r0 + row) * 256 + half * 128;
    float s = 0.f, sq = 0.f;
    for (int i = 0; i < 32; i++) {
      float4 d = ((const float4*)p)[i];
      s += d.x + d.y + d.z + d.w;
      sq += d.x * d.x + d.y * d.y + d.z * d.z + d.w * d.w;
    }
    s_red[tid][0] = s; s_red[tid][1] = sq;
  }
  __syncthreads();
  if (tid < 128) {
    float s  = s_red[2 * tid][0] + s_red[2 * tid + 1][0];
    float sq = s_red[2 * tid][1] + s_red[2 * tid + 1][1];
    float m = s * (1.f / 256.f);
    float v = sq * (1.f / 256.f) - m * m;
    s_mean[tid] = m; s_rstd[tid] = rsqrtf(v + 1e-5f);
  }

  floatx4 acc[2][8];
  for (int rt = 0; rt < 2; rt++)
    for (int ct = 0; ct < 8; ct++) acc[rt][ct] = (floatx4){0.f, 0.f, 0.f, 0.f};

  for (int c = 0; c < 4; c++) {
    __syncthreads();
    for (int i = 0; i < 4; i++) {
      int g = tid + 256 * i;
      int row = g >> 3, c8 = g & 7;
      int col0 = c * 64 + c8 * 8;
      const float* p = x + (r0 + row) * 256 + col0;
      float4 d0 = ((const float4*)p)[0];
      float4 d1 = ((const float4*)p)[1];
      float f[8] = {d0.x, d0.y, d0.z, d0.w, d1.x, d1.y, d1.z, d1.w};
      float m = s_mean[row], rs = s_rstd[row];
      half8 hv;
      #pragma unroll
      for (int j = 0; j < 8; j++)
        hv[j] = (_Float16)((f[j] - m) * rs * s_lnw[col0 + j] + s_lnb[col0 + j]);
      *(half8*)&u.s.A[row][c8 * 8] = hv;
      *(half8*)&u.s.B[row][c8 * 8] = *(const half8*)(WT + (size_t)(y * 128 + row) * 256 + col0);
    }
    __syncthreads();
    #pragma unroll
    for (int ks = 0; ks < 2; ks++) {
      half8 af[2];
      af[0] = *(const half8*)&u.s.A[(2 * w) * 16 + l15][ks * 32 + quad * 8];
      af[1] = *(const half8*)&u.s.A[(2 * w + 1) * 16 + l15][ks * 32 + quad * 8];
      #pragma unroll
      for (int ct = 0; ct < 8; ct++) {
        half8 bf = *(const half8*)&u.s.B[ct * 16 + l15][ks * 32 + quad * 8];
        acc[0][ct] = MFMA_F16(af[0], bf, acc[0][ct]);
        acc[1][ct] = MFMA_F16(af[1], bf, acc[1][ct]);
      }
    }
  }

  const size_t bt = (size_t)(bx >> 3);
  const int n0loc = (bx & 7) * 128;
  if (y == 0) {
    for (int rt = 0; rt < 2; rt++)
      for (int ct = 0; ct < 8; ct++)
        #pragma unroll
        for (int r = 0; r < 4; r++) {
          size_t row = r0 + (2 * w + rt) * 16 + quad * 4 + r;
          kout[row * 128 + ct * 16 + l15] = (_Float16)acc[rt][ct][r];
        }
  } else {
    __syncthreads();
    for (int rt = 0; rt < 2; rt++)
      for (int ct = 0; ct < 8; ct++)
        #pragma unroll
        for (int r = 0; r < 4; r++)
          u.C[(2 * w + rt) * 16 + quad * 4 + r][ct * 16 + l15] = (_Float16)acc[rt][ct][r];
    __syncthreads();
    int s = tid >> 1, hf = tid & 1;
    for (int j = 0; j < 8; j++) {
      int nb = hf * 64 + j * 8;
      half8 tmp;
      #pragma unroll
      for (int e = 0; e < 8; e++) tmp[e] = u.C[nb + e][s];
      *(half8*)(vTout + (bt * 128 + s) * 1024 + n0loc + nb) = tmp;
    }
  }
}

// ---------------------------------------------------------------------------
// phase 2: slot-attention scan. grid 16 (one block per batch), 1024 threads.
// Round-6: ZERO device barriers. Each block owns a full batch: all 1024 n
// rows, k/v read directly from L2 (no LDS staging), reductions block-local.
// vsum computed free via attn-matrix row 8 == 1.0 inside the updates MFMA.
// colsum via per-wave partials summed in fixed order (deterministic).
// ---------------------------------------------------------------------------
struct P2Args {
  const _Float16 *kbuf, *vT;
  const _Float16 *Wih, *Whh, *W1T, *W2T;
  const _Float16 *pQT, *pKT, *pVT, *pOT, *pF1T, *pF2T;
  const float *noise, *mu, *lsig;
  const float *lnsw, *lnsb, *lnmw, *lnmb;
  const float *bih, *bhh, *mb1, *mb2;
  const float *pl1w, *pl1b, *pl2w, *pl2b, *fb1, *fb2, *plfw, *plfb;
  float *out_slots, *out_attn;
};

struct SH {
  float slots[8][128];
  _Float16 a16[16][136];
  _Float16 h16[16][136];
  float gi[8][384];
  float gh[8][384];
  union {
    struct { _Float16 attnT[16][1032]; float updh[2][9][128]; float wcs[16][8]; } sa;
    struct { _Float16 m16[16][264]; } mlp;
    struct { float qh[8][128]; float kh[8][128]; float vh[8][128]; float sc[4][8][8]; } mha;
    struct { _Float16 f16[16][520]; } ffn;
  } u;
  float bih[384], bhh[384], mb1[256], mb2[128], fb1[512], fb2[128];
  float lnsw[128], lnsb[128], lnmw[128], lnmb[128];
  float pl1w[128], pl1b[128], pl2w[128], pl2b[128], plfw[128], plfb[128];
};

__device__ __forceinline__ void ln_to_a16(SH* sh, const float (*src)[128],
                                          const float* wv, const float* bv,
                                          int w, int lane) {
  if (w < 8) {
    float x0 = src[w][lane], x1 = src[w][lane + 64];
    float s = x0 + x1, sq = x0 * x0 + x1 * x1;
    #pragma unroll
    for (int m = 1; m < 64; m <<= 1) { s += __shfl_xor(s, m); sq += __shfl_xor(sq, m); }
    float mn = s * 0.0078125f;
    float vr = sq * 0.0078125f - mn * mn;
    float rs = rsqrtf(vr + 1e-5f);
    sh->a16[w][lane]      = (_Float16)((x0 - mn) * rs * wv[lane]      + bv[lane]);
    sh->a16[w][lane + 64] = (_Float16)((x1 - mn) * rs * wv[lane + 64] + bv[lane + 64]);
  } else {
    sh->a16[w][lane] = (_Float16)0.f;
    sh->a16[w][lane + 64] = (_Float16)0.f;
  }
}

__global__ __launch_bounds__(1024, 4) void slot_attn_kernel(P2Args P) {
  __shared__ SH sh;
  const int tid = threadIdx.x;
  const int w = tid >> 6, lane = tid & 63, quad = lane >> 4, l15 = lane & 15;
  const int b = blockIdx.x;            // one block per batch

  for (int i = tid; i < 384; i += 1024) { sh.bih[i] = P.bih[i]; sh.bhh[i] = P.bhh[i]; }
  for (int i = tid; i < 256; i += 1024) sh.mb1[i] = P.mb1[i];
  for (int i = tid; i < 512; i += 1024) sh.fb1[i] = P.fb1[i];
  if (tid < 128) {
    sh.mb2[tid]  = P.mb2[tid];  sh.fb2[tid]  = P.fb2[tid];
    sh.lnsw[tid] = P.lnsw[tid]; sh.lnsb[tid] = P.lnsb[tid];
    sh.lnmw[tid] = P.lnmw[tid]; sh.lnmb[tid] = P.lnmb[tid];
    sh.pl1w[tid] = P.pl1w[tid]; sh.pl1b[tid] = P.pl1b[tid];
    sh.pl2w[tid] = P.pl2w[tid]; sh.pl2b[tid] = P.pl2b[tid];
    sh.plfw[tid] = P.plfw[tid]; sh.plfb[tid] = P.plfb[tid];
  }
  {
    int kk = tid >> 7, s = tid & 127;
    float v = P.mu[s] + expf(P.lsig[s]) * P.noise[(b * 8 + kk) * 128 + s];
    sh.slots[kk][s] = v;
    sh.h16[kk][s] = (_Float16)v;
  }
  if (w >= 8) {   // zero pad rows 8..15 of a16/h16 (never written again)
    sh.a16[w][lane] = (_Float16)0.f; sh.a16[w][lane + 64] = (_Float16)0.f;
    sh.h16[w][lane] = (_Float16)0.f; sh.h16[w][lane + 64] = (_Float16)0.f;
  }
  __syncthreads();

  for (int t = 0; t < 12; t++) {
    const _Float16* kt = P.kbuf + ((size_t)(b * 12 + t)) * 1024 * 128;
    const _Float16* vt = P.vT   + ((size_t)(b * 12 + t)) * 128 * 1024;

    for (int it = 0; it < 3; it++) {
      // ---- ph1: w<8: LN(slots) -> a16 rows 0..7 ; w>=8: gh (all 24 tiles)
      if (w < 8) {
        float x0 = sh.slots[w][lane], x1 = sh.slots[w][lane + 64];
        float s = x0 + x1, sq = x0 * x0 + x1 * x1;
        #pragma unroll
        for (int m = 1; m < 64; m <<= 1) { s += __shfl_xor(s, m); sq += __shfl_xor(sq, m); }
        float mn = s * 0.0078125f;
        float vr = sq * 0.0078125f - mn * mn;
        float rs = rsqrtf(vr + 1e-5f);
        sh.a16[w][lane]      = (_Float16)((x0 - mn) * rs * sh.lnsw[lane]      + sh.lnsb[lane]);
        sh.a16[w][lane + 64] = (_Float16)((x1 - mn) * rs * sh.lnsw[lane + 64] + sh.lnsb[lane + 64]);
      } else {
        const int idx8 = w - 8;
        const _Float16* ar = &sh.h16[l15][quad * 8];
        #pragma unroll
        for (int tt = 0; tt < 3; tt++) {
          int ct = idx8 + tt * 8;
          const _Float16* Bg = P.Whh + (size_t)(ct * 16 + l15) * 128 + quad * 8;
          floatx4 acc = (floatx4){0.f, 0.f, 0.f, 0.f};
          #pragma unroll
          for (int ks = 0; ks < 4; ks++)
            acc = MFMA_F16(*(const half8*)(ar + ks * 32), *(const half8*)(Bg + ks * 32), acc);
          int col = ct * 16 + l15;
          #pragma unroll
          for (int r = 0; r < 4; r++) {
            int slot = quad * 4 + r;
            if (slot < 8) sh.gh[slot][col] = acc[r] + sh.bhh[col];
          }
        }
      }
      __syncthreads();
      // ---- ph2: ALL waves: logits over 4 n-tiles each, softmax, attnT, colsum
      {
        floatx4 accs[4];
        #pragma unroll
        for (int tt = 0; tt < 4; tt++) {
          int nbase = (w + tt * 16) * 16;
          floatx4 acc = (floatx4){0.f, 0.f, 0.f, 0.f};
          const _Float16* ar = kt + (size_t)(nbase + l15) * 128 + quad * 8;
          const _Float16* br = &sh.a16[l15][quad * 8];
          #pragma unroll
          for (int ks = 0; ks < 4; ks++)
            acc = MFMA_F16(*(const half8*)(ar + ks * 32), *(const half8*)(br + ks * 32), acc);
          accs[tt] = acc;
        }
        float cs = 0.f;
        #pragma unroll
        for (int tt = 0; tt < 4; tt++) {
          int nbase = (w + tt * 16) * 16;
          #pragma unroll
          for (int r = 0; r < 4; r++) {
            float v = (l15 < 8) ? accs[tt][r] : -3.0e38f;
            float mx = v;
            mx = fmaxf(mx, __shfl_xor(mx, 1, 16));
            mx = fmaxf(mx, __shfl_xor(mx, 2, 16));
            mx = fmaxf(mx, __shfl_xor(mx, 4, 16));
            mx = fmaxf(mx, __shfl_xor(mx, 8, 16));
            float pv = (l15 < 8) ? expf(v - mx) : 0.f;
            float ss = pv;
            ss += __shfl_xor(ss, 1, 16); ss += __shfl_xor(ss, 2, 16);
            ss += __shfl_xor(ss, 4, 16); ss += __shfl_xor(ss, 8, 16);
            float pn = pv / ss;
            cs += pn;
            int n = nbase + quad * 4 + r;
            sh.u.sa.attnT[l15][n] = (l15 == 8) ? (_Float16)1.f : (_Float16)pn;
            if (it == 2 && l15 < 8)
              P.out_attn[((size_t)(b * 12 + t) * 1024 + n) * 8 + l15] = pn;
          }
        }
        cs += __shfl_xor(cs, 16); cs += __shfl_xor(cs, 32);
        if (lane < 8) sh.u.sa.wcs[w][lane] = cs;
      }
      __syncthreads();
      // ---- ph3: ALL waves: updates halves  upd[slot][scol] += P^T v ; row8 = vsum
      {
        int tcol = w & 7, h = w >> 3;
        floatx4 acc = (floatx4){0.f, 0.f, 0.f, 0.f};
        const _Float16* ar = &sh.u.sa.attnT[l15][h * 512 + quad * 8];
        const _Float16* br = vt + (size_t)(tcol * 16 + l15) * 1024 + h * 512 + quad * 8;
        #pragma unroll 4
        for (int ks = 0; ks < 16; ks++)
          acc = MFMA_F16(*(const half8*)(ar + ks * 32), *(const half8*)(br + ks * 32), acc);
        int scol = tcol * 16 + l15;
        #pragma unroll
        for (int r = 0; r < 4; r++) {
          int row = quad * 4 + r;
          if (row < 9) sh.u.sa.updh[h][row][scol] = acc[r];
        }
      }
      __syncthreads();
      // ---- ph4: normalize -> a16 rows 0..7 (eps renorm folded; vsum = row 8)
      {
        int slot = tid >> 7, scol = tid & 127;
        float sum = sh.u.sa.updh[0][slot][scol] + sh.u.sa.updh[1][slot][scol];
        float vs  = sh.u.sa.updh[0][8][scol]    + sh.u.sa.updh[1][8][scol];
        float csum = 0.f;
        #pragma unroll
        for (int ww = 0; ww < 16; ww++) csum += sh.u.sa.wcs[ww][slot];
        float upd = (sum + 1e-8f * vs) / (csum + 1024.f * 1e-8f);
        sh.a16[slot][scol] = (_Float16)upd;
      }
      __syncthreads();
      // ---- ph5: GRU gi: all waves tile ct=w; w<8 also ct=16+w
      {
        const _Float16* ar = &sh.a16[l15][quad * 8];
        const _Float16* Bg = P.Wih + (size_t)(w * 16 + l15) * 128 + quad * 8;
        floatx4 acc = (floatx4){0.f, 0.f, 0.f, 0.f};
        #pragma unroll
        for (int ks = 0; ks < 4; ks++)
          acc = MFMA_F16(*(const half8*)(ar + ks * 32), *(const half8*)(Bg + ks * 32), acc);
        int col = w * 16 + l15;
        #pragma unroll
        for (int r = 0; r < 4; r++) {
          int slot = quad * 4 + r;
          if (slot < 8) sh.gi[slot][col] = acc[r] + sh.bih[col];
        }
        if (w < 8) {
          int col2 = (16 + w) * 16 + l15;
          const _Float16* Bg2 = P.Wih + (size_t)((16 + w) * 16 + l15) * 128 + quad * 8;
          floatx4 acc2 = (floatx4){0.f, 0.f, 0.f, 0.f};
          #pragma unroll
          for (int ks = 0; ks < 4; ks++)
            acc2 = MFMA_F16(*(const half8*)(ar + ks * 32), *(const half8*)(Bg2 + ks * 32), acc2);
          #pragma unroll
          for (int r = 0; r < 4; r++) {
            int slot = quad * 4 + r;
            if (slot < 8) sh.gi[slot][col2] = acc2[r] + sh.bih[col2];
          }
        }
      }
      __syncthreads();
      // ---- ph6: gates + LN fused (waves 0-7); writes slots + a16 (lnm / pl1)
      if (w < 8) {
        float h0 = sh.slots[w][lane], h1 = sh.slots[w][lane + 64];
        float r0 = 1.f / (1.f + expf(-(sh.gi[w][lane]       + sh.gh[w][lane])));
        float z0 = 1.f / (1.f + expf(-(sh.gi[w][128 + lane] + sh.gh[w][128 + lane])));
        float n0v = tanhf(sh.gi[w][256 + lane] + r0 * sh.gh[w][256 + lane]);
        float x0 = (1.f - z0) * n0v + z0 * h0;
        int l64 = lane + 64;
        float r1 = 1.f / (1.f + expf(-(sh.gi[w][l64]       + sh.gh[w][l64])));
        float z1 = 1.f / (1.f + expf(-(sh.gi[w][128 + l64] + sh.gh[w][128 + l64])));
        float n1v = tanhf(sh.gi[w][256 + l64] + r1 * sh.gh[w][256 + l64]);
        float x1 = (1.f - z1) * n1v + z1 * h1;
        sh.slots[w][lane] = x0; sh.slots[w][lane + 64] = x1;
        if (it == 2) {
          P.out_slots[((size_t)(b * 12 + t) * 8 + w) * 128 + lane]      = x0;
          P.out_slots[((size_t)(b * 12 + t) * 8 + w) * 128 + lane + 64] = x1;
        }
        const float* wv = (it < 2) ? sh.lnmw : sh.pl1w;
        const float* bv = (it < 2) ? sh.lnmb : sh.pl1b;
        float s = x0 + x1, sq = x0 * x0 + x1 * x1;
        #pragma unroll
        for (int m = 1; m < 64; m <<= 1) { s += __shfl_xor(s, m); sq += __shfl_xor(sq, m); }
        float mn = s * 0.0078125f;
        float vr = sq * 0.0078125f - mn * mn;
        float rs = rsqrtf(vr + 1e-5f);
        sh.a16[w][lane]      = (_Float16)((x0 - mn) * rs * wv[lane]      + bv[lane]);
        sh.a16[w][lane + 64] = (_Float16)((x1 - mn) * rs * wv[lane + 64] + bv[lane + 64]);
      }
      __syncthreads();
      // ---- residual MLP (iters 0,1)
      if (it < 2) {
        {
          floatx4 acc = (floatx4){0.f, 0.f, 0.f, 0.f};
          const _Float16* ar = &sh.a16[l15][quad * 8];
          const _Float16* br = P.W1T + (size_t)(w * 16 + l15) * 128 + quad * 8;
          #pragma unroll
          for (int ks = 0; ks < 4; ks++)
            acc = MFMA_F16(*(const half8*)(ar + ks * 32), *(const half8*)(br + ks * 32), acc);
          int col = w * 16 + l15;
          #pragma unroll
          for (int r = 0; r < 4; r++) {
            int slot = quad * 4 + r;
            if (slot < 8) sh.u.mlp.m16[slot][col] = (_Float16)fmaxf(acc[r] + sh.mb1[col], 0.f);
            else          sh.u.mlp.m16[slot][col] = (_Float16)0.f;
          }
        }
        __syncthreads();
        if (w < 8) {   // MLP2 + residual; refresh h16 (GRU h-input for next it)
          floatx4 acc = (floatx4){0.f, 0.f, 0.f, 0.f};
          const _Float16* ar = &sh.u.mlp.m16[l15][quad * 8];
          const _Float16* br = P.W2T + (size_t)(w * 16 + l15) * 256 + quad * 8;
          #pragma unroll
          for (int ks = 0; ks < 8; ks++)
            acc = MFMA_F16(*(const half8*)(ar + ks * 32), *(const half8*)(br + ks * 32), acc);
          int col = w * 16 + l15;
          #pragma unroll
          for (int r = 0; r < 4; r++) {
            int slot = quad * 4 + r;
            if (slot < 8) {
              float ns = sh.slots[slot][col] + acc[r] + sh.mb2[col];
              sh.slots[slot][col] = ns;
              sh.h16[slot][col] = (_Float16)ns;
            }
          }
        }
        __syncthreads();
      }
    } // it

    // ---- predictor; a16 = LN_pl1(slots) from gates phase
    {
      const _Float16* ar = &sh.a16[l15][quad * 8];
      int gg = w >> 3, ct = w & 7, col = ct * 16 + l15;
      const _Float16* Bg = (gg == 0 ? P.pQT : P.pKT) + (size_t)(ct * 16 + l15) * 128 + quad * 8;
      floatx4 acc = (floatx4){0.f, 0.f, 0.f, 0.f};
      #pragma unroll
      for (int ks = 0; ks < 4; ks++)
        acc = MFMA_F16(*(const half8*)(ar + ks * 32), *(const half8*)(Bg + ks * 32), acc);
      float scale = (gg == 0) ? 0.17677669529663687f : 1.f;
      float* dst = (gg == 0) ? &sh.u.mha.qh[0][0] : &sh.u.mha.kh[0][0];
      #pragma unroll
      for (int r = 0; r < 4; r++) {
        int slot = quad * 4 + r;
        if (slot < 8) dst[slot * 128 + col] = acc[r] * scale;
      }
      if (w < 8) {
        const _Float16* Bg2 = P.pVT + (size_t)(w * 16 + l15) * 128 + quad * 8;
        floatx4 a2 = (floatx4){0.f, 0.f, 0.f, 0.f};
        #pragma unroll
        for (int ks = 0; ks < 4; ks++)
          a2 = MFMA_F16(*(const half8*)(ar + ks * 32), *(const half8*)(Bg2 + ks * 32), a2);
        int colv = w * 16 + l15;
        #pragma unroll
        for (int r = 0; r < 4; r++) {
          int slot = quad * 4 + r;
          if (slot < 8) sh.u.mha.vh[slot][colv] = a2[r];
        }
      }
    }
    __syncthreads();
    // ---- fused mha: scores + softmax + P@V, one wave per head (w<4)
    if (w < 4) {
      int h = w, a = lane >> 3, b2 = lane & 7;
      const float* qr = &sh.u.mha.qh[a][h * 32];
      const float* kr = &sh.u.mha.kh[b2][h * 32];
      float s = 0.f;
      #pragma unroll
      for (int d = 0; d < 32; d++) s += qr[d] * kr[d];
      float mx = s;
      mx = fmaxf(mx, __shfl_xor(mx, 1, 8));
      mx = fmaxf(mx, __shfl_xor(mx, 2, 8));
      mx = fmaxf(mx, __shfl_xor(mx, 4, 8));
      float e = expf(s - mx);
      float ssum = e;
      ssum += __shfl_xor(ssum, 1, 8); ssum += __shfl_xor(ssum, 2, 8); ssum += __shfl_xor(ssum, 4, 8);
      float p = e / ssum;
      float o0 = 0.f, o1 = 0.f, o2 = 0.f, o3 = 0.f;
      int d0 = h * 32 + b2 * 4;
      #pragma unroll
      for (int j = 0; j < 8; j++) {
        float pj = __shfl(p, (a << 3) + j);
        const float* vr = &sh.u.mha.vh[j][d0];
        o0 += pj * vr[0]; o1 += pj * vr[1]; o2 += pj * vr[2]; o3 += pj * vr[3];
      }
      sh.a16[a][d0]     = (_Float16)o0;
      sh.a16[a][d0 + 1] = (_Float16)o1;
      sh.a16[a][d0 + 2] = (_Float16)o2;
      sh.a16[a][d0 + 3] = (_Float16)o3;
    }
    __syncthreads();
    if (w < 8) {       // s += o @ Wo
      floatx4 acc = (floatx4){0.f, 0.f, 0.f, 0.f};
      const _Float16* ar = &sh.a16[l15][quad * 8];
      const _Float16* br = P.pOT + (size_t)(w * 16 + l15) * 128 + quad * 8;
      #pragma unroll
      for (int ks = 0; ks < 4; ks++)
        acc = MFMA_F16(*(const half8*)(ar + ks * 32), *(const half8*)(br + ks * 32), acc);
      int col = w * 16 + l15;
      #pragma unroll
      for (int r = 0; r < 4; r++) {
        int slot = quad * 4 + r;
        if (slot < 8) sh.slots[slot][col] += acc[r];
      }
    }
    __syncthreads();
    ln_to_a16(&sh, sh.slots, sh.pl2w, sh.pl2b, w, lane);
    __syncthreads();
    for (int ct = w; ct < 32; ct += 16) {   // FFN1 + relu
      floatx4 acc = (floatx4){0.f, 0.f, 0.f, 0.f};
      const _Float16* ar = &sh.a16[l15][quad * 8];
      const _Float16* br = P.pF1T + (size_t)(ct * 16 + l15) * 128 + quad * 8;
      #pragma unroll
      for (int ks = 0; ks < 4; ks++)
        acc = MFMA_F16(*(const half8*)(ar + ks * 32), *(const half8*)(br + ks * 32), acc);
      int col = ct * 16 + l15;
      #pragma unroll
      for (int r = 0; r < 4; r++) {
        int slot = quad * 4 + r;
        if (slot < 8) sh.u.ffn.f16[slot][col] = (_Float16)fmaxf(acc[r] + sh.fb1[col], 0.f);
        else          sh.u.ffn.f16[slot][col] = (_Float16)0.f;
      }
    }
    __syncthreads();
    if (w < 8) {       // FFN2 + residual
      floatx4 acc = (floatx4){0.f, 0.f, 0.f, 0.f};
      const _Float16* ar = &sh.u.ffn.f16[l15][quad * 8];
      const _Float16* br = P.pF2T + (size_t)(w * 16 + l15) * 512 + quad * 8;
      #pragma unroll 4
      for (int ks = 0; ks < 16; ks++)
        acc = MFMA_F16(*(const half8*)(ar + ks * 32), *(const half8*)(br + ks * 32), acc);
      int col = w * 16 + l15;
      #pragma unroll
      for (int r = 0; r < 4; r++) {
        int slot = quad * 4 + r;
        if (slot < 8) sh.slots[slot][col] += acc[r] + sh.fb2[col];
      }
    }
    __syncthreads();
    if (w < 8) {       // final LN -> carry; refresh h16 for next t
      float x0 = sh.slots[w][lane], x1 = sh.slots[w][lane + 64];
      float s = x0 + x1, sq = x0 * x0 + x1 * x1;
      #pragma unroll
      for (int m = 1; m < 64; m <<= 1) { s += __shfl_xor(s, m); sq += __shfl_xor(sq, m); }
      float mn = s * 0.0078125f;
      float vr = sq * 0.0078125f - mn * mn;
      float rs = rsqrtf(vr + 1e-5f);
      float y0 = (x0 - mn) * rs * sh.plfw[lane]      + sh.plfb[lane];
      float y1 = (x1 - mn) * rs * sh.plfw[lane + 64] + sh.plfb[lane + 64];
      sh.slots[w][lane] = y0;      sh.slots[w][lane + 64] = y1;
      sh.h16[w][lane] = (_Float16)y0; sh.h16[w][lane + 64] = (_Float16)y1;
    }
    __syncthreads();
  } // t
}

// ---------------------------------------------------------------------------
extern "C" void kernel_launch(void* const* d_in, const int* in_sizes, int n_in,
                              void* d_out, int out_size, void* d_ws, size_t ws_size,
                              hipStream_t stream) {
  const float* inp   = (const float*)d_in[0];
  const float* noise = (const float*)d_in[1];
  const float* mu    = (const float*)d_in[2];
  const float* lsig  = (const float*)d_in[3];
  const float* lniw  = (const float*)d_in[4];
  const float* lnib  = (const float*)d_in[5];
  const float* lnsw  = (const float*)d_in[6];
  const float* lnsb  = (const float*)d_in[7];
  const float* lnmw  = (const float*)d_in[8];
  const float* lnmb  = (const float*)d_in[9];
  const float* Wq    = (const float*)d_in[10];
  const float* Wk    = (const float*)d_in[11];
  const float* Wv    = (const float*)d_in[12];
  const float* gWih  = (const float*)d_in[13];
  const float* gWhh  = (const float*)d_in[14];
  const float* gbih  = (const float*)d_in[15];
  const float* gbhh  = (const float*)d_in[16];
  const float* mW1   = (const float*)d_in[17];
  const float* mb1   = (const float*)d_in[18];
  const float* mW2   = (const float*)d_in[19];
  const float* mb2   = (const float*)d_in[20];
  const float* pl1w  = (const float*)d_in[21];
  const float* pl1b  = (const float*)d_in[22];
  const float* pWq   = (const float*)d_in[23];
  const float* pWk   = (const float*)d_in[24];
  const float* pWv   = (const float*)d_in[25];
  const float* pWo   = (const float*)d_in[26];
  const float* pl2w  = (const float*)d_in[27];
  const float* pl2b  = (const float*)d_in[28];
  const float* pf1   = (const float*)d_in[29];
  const float* pfb1  = (const float*)d_in[30];
  const float* pf2   = (const float*)d_in[31];
  const float* pfb2  = (const float*)d_in[32];
  const float* plfw  = (const float*)d_in[33];
  const float* plfb  = (const float*)d_in[34];

  // workspace layout (f16 elements)
  _Float16* p   = (_Float16*)d_ws;
  _Float16* kbuf = p;  p += 25165824;
  _Float16* vT   = p;  p += 25165824;
  _Float16* WT   = p;  p += 65536;
  _Float16* WqT  = p;  p += 16384;   // unused (k~ fold), kept for layout
  _Float16* Wih  = p;  p += 49152;
  _Float16* Whh  = p;  p += 49152;
  _Float16* W1T  = p;  p += 32768;
  _Float16* W2T  = p;  p += 32768;
  _Float16* pQT  = p;  p += 16384;
  _Float16* pKT  = p;  p += 16384;
  _Float16* pVT  = p;  p += 16384;
  _Float16* pOT  = p;  p += 16384;
  _Float16* pF1T = p;  p += 65536;
  _Float16* pF2T = p;  p += 65536;
  (void)WqT;

  const float kscale = 0.08838834764831845f;  // S^-0.5, S=128

  PrepJobs J;
  const float* srcs[11] = {Wv, gWih, gWhh, mW1, mW2, pWq, pWk, pWv, pWo, pf1, pf2};
  _Float16* dsts[11]    = {WT + 32768, Wih, Whh, W1T, W2T, pQT, pKT, pVT, pOT, pF1T, pF2T};
  int Ins[11]    = {256, 49152, 49152, 128, 256, 128, 128, 128, 128, 128, 512};
  int Outs[11]   = {128, 1, 1, 256, 128, 128, 128, 128, 128, 512, 128};
  int elemss[11] = {32768, 49152, 49152, 32768, 32768, 16384, 16384, 16384, 16384, 65536, 65536};
  int doTs[11]   = {1, 0, 0, 1, 1, 1, 1, 1, 1, 1, 1};
  float scales[11] = {1.f, 1.f, 1.f, 1.f, 1.f, 1.f, 1.f, 1.f, 1.f, 1.f, 1.f};
  for (int j = 0; j < 11; j++) {
    J.src[j] = srcs[j]; J.dst[j] = dsts[j]; J.In[j] = Ins[j]; J.Out[j] = Outs[j];
    J.elems[j] = elemss[j]; J.doT[j] = doTs[j]; J.scale[j] = scales[j];
  }
  dim3 gp(256, 11, 1);
  prep_all_kernel<<<gp, 256, 0, stream>>>(J);
  prep_wtilde_kernel<<<128, 256, 0, stream>>>(Wk, Wq, WT, kscale);

  dim3 g1(1536, 2, 1);
  gemm_kv_kernel<<<g1, 256, 0, stream>>>(inp, lniw, lnib, WT, kbuf, vT);

  P2Args a;
  a.kbuf = kbuf; a.vT = vT;
  a.Wih = Wih; a.Whh = Whh; a.W1T = W1T; a.W2T = W2T;
  a.pQT = pQT; a.pKT = pKT; a.pVT = pVT; a.pOT = pOT; a.pF1T = pF1T; a.pF2T = pF2T;
  a.noise = noise; a.mu = mu; a.lsig = lsig;
  a.lnsw = lnsw; a.lnsb = lnsb; a.lnmw = lnmw; a.lnmb = lnmb;
  a.bih = gbih; a.bhh = gbhh; a.mb1 = mb1; a.mb2 = mb2;
  a.pl1w = pl1w; a.pl1b = pl1b; a.pl2w = pl2w; a.pl2b = pl2b;
  a.fb1 = pfb1; a.fb2 = pfb2; a.plfw = plfw; a.plfb = plfb;
  a.out_slots = (float*)d_out;
  a.out_attn  = (float*)d_out + 196608;

  slot_attn_kernel<<<16, 1024, 0, stream>>>(a);
}

// Round 7
// 1388.995 us; speedup vs baseline: 1.3796x; 1.3796x over previous
//
#include <hip/hip_runtime.h>
#include <hip/hip_bf16.h>

typedef _Float16 half8 __attribute__((ext_vector_type(8)));
typedef float floatx4 __attribute__((ext_vector_type(4)));

#define MFMA_F16(a, b, c) __builtin_amdgcn_mfma_f32_16x16x32_f16((a), (b), (c), 0, 0, 0)

// ---------------------------------------------------------------------------
// fused prep: 11 f32->f16 (optional transpose, scale) jobs in one launch.
// ---------------------------------------------------------------------------
struct PrepJobs {
  const float* src[11];
  _Float16* dst[11];
  int In[11], Out[11], elems[11], doT[11];
  float scale[11];
};

__global__ void prep_all_kernel(PrepJobs J) {
  int j = blockIdx.y;
  int idx = blockIdx.x * 256 + threadIdx.x;
  if (idx >= J.elems[j]) return;
  float v;
  if (J.doT[j]) { int o = idx / J.In[j], i = idx - o * J.In[j]; v = J.src[j][i * J.Out[j] + o]; }
  else          { v = J.src[j][idx]; }
  J.dst[j][idx] = (_Float16)(v * J.scale[j]);
}

// W~T[s][i] = kscale * sum_o Wk[i][o] * Wq[s][o]   (folds Wq into the k GEMM)
__global__ void prep_wtilde_kernel(const float* __restrict__ Wk, const float* __restrict__ Wq,
                                   _Float16* __restrict__ WT, float scale) {
  int idx = blockIdx.x * 256 + threadIdx.x;   // 32768 = 128 s * 256 i
  int s = idx >> 8, i = idx & 255;
  const float* wk = Wk + (size_t)i * 128;
  const float* wq = Wq + (size_t)s * 128;
  float acc = 0.f;
  #pragma unroll 4
  for (int o = 0; o < 128; o++) acc += wk[o] * wq[o];
  WT[idx] = (_Float16)(acc * scale);
}

__global__ void init_ctr_kernel(int* __restrict__ ctr) {
  ctr[threadIdx.x] = 0;   // 1024 ints (16 batches x 64-int stride = 256B pad)
}

// ---------------------------------------------------------------------------
// phase 1: fused LN + dual GEMM.  grid (1536, 2), 256 threads. (unchanged)
// ---------------------------------------------------------------------------
__global__ __launch_bounds__(256) void gemm_kv_kernel(
    const float* __restrict__ x, const float* __restrict__ lnw_g,
    const float* __restrict__ lnb_g, const _Float16* __restrict__ WT,
    _Float16* __restrict__ kout, _Float16* __restrict__ vTout) {
  __shared__ union {
    struct { _Float16 A[128][72]; _Float16 B[128][72]; } s;
    _Float16 C[128][136];
  } u;
  __shared__ float s_mean[128], s_rstd[128], s_red[256][2], s_lnw[256], s_lnb[256];

  const int tid = threadIdx.x;
  const int bx = blockIdx.x, y = blockIdx.y;
  const size_t r0 = (size_t)bx * 128;
  const int w = tid >> 6, lane = tid & 63, quad = lane >> 4, l15 = lane & 15;

  s_lnw[tid] = lnw_g[tid];
  s_lnb[tid] = lnb_g[tid];
  {
    int row = tid >> 1, half = tid & 1;
    const float* p = x + (r0 + row) * 256 + half * 128;
    float s = 0.f, sq = 0.f;
    for (int i = 0; i < 32; i++) {
      float4 d = ((const float4*)p)[i];
      s += d.x + d.y + d.z + d.w;
      sq += d.x * d.x + d.y * d.y + d.z * d.z + d.w * d.w;
    }
    s_red[tid][0] = s; s_red[tid][1] = sq;
  }
  __syncthreads();
  if (tid < 128) {
    float s  = s_red[2 * tid][0] + s_red[2 * tid + 1][0];
    float sq = s_red[2 * tid][1] + s_red[2 * tid + 1][1];
    float m = s * (1.f / 256.f);
    float v = sq * (1.f / 256.f) - m * m;
    s_mean[tid] = m; s_rstd[tid] = rsqrtf(v + 1e-5f);
  }

  floatx4 acc[2][8];
  for (int rt = 0; rt < 2; rt++)
    for (int ct = 0; ct < 8; ct++) acc[rt][ct] = (floatx4){0.f, 0.f, 0.f, 0.f};

  for (int c = 0; c < 4; c++) {
    __syncthreads();
    for (int i = 0; i < 4; i++) {
      int g = tid + 256 * i;
      int row = g >> 3, c8 = g & 7;
      int col0 = c * 64 + c8 * 8;
      const float* p = x + (r0 + row) * 256 + col0;
      float4 d0 = ((const float4*)p)[0];
      float4 d1 = ((const float4*)p)[1];
      float f[8] = {d0.x, d0.y, d0.z, d0.w, d1.x, d1.y, d1.z, d1.w};
      float m = s_mean[row], rs = s_rstd[row];
      half8 hv;
      #pragma unroll
      for (int j = 0; j < 8; j++)
        hv[j] = (_Float16)((f[j] - m) * rs * s_lnw[col0 + j] + s_lnb[col0 + j]);
      *(half8*)&u.s.A[row][c8 * 8] = hv;
      *(half8*)&u.s.B[row][c8 * 8] = *(const half8*)(WT + (size_t)(y * 128 + row) * 256 + col0);
    }
    __syncthreads();
    #pragma unroll
    for (int ks = 0; ks < 2; ks++) {
      half8 af[2];
      af[0] = *(const half8*)&u.s.A[(2 * w) * 16 + l15][ks * 32 + quad * 8];
      af[1] = *(const half8*)&u.s.A[(2 * w + 1) * 16 + l15][ks * 32 + quad * 8];
      #pragma unroll
      for (int ct = 0; ct < 8; ct++) {
        half8 bf = *(const half8*)&u.s.B[ct * 16 + l15][ks * 32 + quad * 8];
        acc[0][ct] = MFMA_F16(af[0], bf, acc[0][ct]);
        acc[1][ct] = MFMA_F16(af[1], bf, acc[1][ct]);
      }
    }
  }

  const size_t bt = (size_t)(bx >> 3);
  const int n0loc = (bx & 7) * 128;
  if (y == 0) {
    for (int rt = 0; rt < 2; rt++)
      for (int ct = 0; ct < 8; ct++)
        #pragma unroll
        for (int r = 0; r < 4; r++) {
          size_t row = r0 + (2 * w + rt) * 16 + quad * 4 + r;
          kout[row * 128 + ct * 16 + l15] = (_Float16)acc[rt][ct][r];
        }
  } else {
    __syncthreads();
    for (int rt = 0; rt < 2; rt++)
      for (int ct = 0; ct < 8; ct++)
        #pragma unroll
        for (int r = 0; r < 4; r++)
          u.C[(2 * w + rt) * 16 + quad * 4 + r][ct * 16 + l15] = (_Float16)acc[rt][ct][r];
    __syncthreads();
    int s = tid >> 1, hf = tid & 1;
    for (int j = 0; j < 8; j++) {
      int nb = hf * 64 + j * 8;
      half8 tmp;
      #pragma unroll
      for (int e = 0; e < 8; e++) tmp[e] = u.C[nb + e][s];
      *(half8*)(vTout + (bt * 128 + s) * 1024 + n0loc + nb) = tmp;
    }
  }
}

// ---------------------------------------------------------------------------
// phase 2: slot-attention scan. grid 128 (= 16 batches x 8 n-groups), 1024 thr.
// Round-7 (base = round-5's 810us): row8-vsum trick (vsum phase deleted);
// gi+gates merged in-register (gi LDS array deleted, 1 sync saved); gh all in
// ph1 on waves 8-15; softmax split over all 16 waves (serial chain halved);
// deterministic colsum via per-wave partials.
// ---------------------------------------------------------------------------
struct P2Args {
  const _Float16 *kbuf, *vT;
  const _Float16 *Wih, *Whh, *W1T, *W2T;
  const _Float16 *pQT, *pKT, *pVT, *pOT, *pF1T, *pF2T;
  const float *noise, *mu, *lsig;
  const float *lnsw, *lnsb, *lnmw, *lnmb;
  const float *bih, *bhh, *mb1, *mb2;
  const float *pl1w, *pl1b, *pl2w, *pl2b, *fb1, *fb2, *plfw, *plfb;
  float *out_slots, *out_attn;
  float *upd_p;   // [2][16][8][9][128]
  float *col_p;   // [2][16][8][64]  (8 used, 256B padded)
  int   *ctr;     // [16][64]        (1 used, 256B padded)
};

struct SH {
  _Float16 k_lds[128][136];   // k~ slice [n_local][s]
  _Float16 v_lds[128][136];   // v slice [s][n_local]
  float slots[8][128];
  _Float16 a16[16][136];
  _Float16 h16[16][136];
  float gh[8][384];
  union {
    struct { _Float16 attnT[16][136]; float wcs[16][8]; } sa;
    struct { _Float16 m16[16][264]; } mlp;
    struct { float qh[8][128]; float kh[8][128]; float vh[8][128]; float sc[4][8][8]; } mha;
    struct { _Float16 f16[16][520]; } ffn;
  } u;
  float bih[384], bhh[384], mb1[256], mb2[128], fb1[512], fb2[128];
  float lnsw[128], lnsb[128], lnmw[128], lnmb[128];
  float pl1w[128], pl1b[128], pl2w[128], pl2b[128], plfw[128], plfb[128];
};

__device__ __forceinline__ void group_barrier(int* ctr, int target) {
  __syncthreads();   // drains vmcnt: all agent-scope stores complete
  if (threadIdx.x == 0) {
    __hip_atomic_fetch_add(ctr, 1, __ATOMIC_ACQ_REL, __HIP_MEMORY_SCOPE_AGENT);
    while (__hip_atomic_load(ctr, __ATOMIC_ACQUIRE, __HIP_MEMORY_SCOPE_AGENT) < target)
      __builtin_amdgcn_s_sleep(1);
  }
  __syncthreads();
}

__device__ __forceinline__ void ln_to_a16(SH* sh, const float (*src)[128],
                                          const float* wv, const float* bv,
                                          int w, int lane) {
  if (w < 8) {
    float x0 = src[w][lane], x1 = src[w][lane + 64];
    float s = x0 + x1, sq = x0 * x0 + x1 * x1;
    #pragma unroll
    for (int m = 1; m < 64; m <<= 1) { s += __shfl_xor(s, m); sq += __shfl_xor(sq, m); }
    float mn = s * 0.0078125f;
    float vr = sq * 0.0078125f - mn * mn;
    float rs = rsqrtf(vr + 1e-5f);
    sh->a16[w][lane]      = (_Float16)((x0 - mn) * rs * wv[lane]      + bv[lane]);
    sh->a16[w][lane + 64] = (_Float16)((x1 - mn) * rs * wv[lane + 64] + bv[lane + 64]);
  }
}

__global__ __launch_bounds__(1024, 4) void slot_attn_kernel(P2Args P) {
  __shared__ SH sh;
  const int tid = threadIdx.x;
  const int w = tid >> 6, lane = tid & 63, quad = lane >> 4, l15 = lane & 15;
  const int b = blockIdx.x & 15;       // batch
  const int g = blockIdx.x >> 4;       // n-group (0..7); same XCD for fixed b
  const int n0 = g * 128;
  int* ctrb = P.ctr + b * 64;          // 256B-padded counter
  int bar_phase = 0;

  for (int i = tid; i < 384; i += 1024) { sh.bih[i] = P.bih[i]; sh.bhh[i] = P.bhh[i]; }
  for (int i = tid; i < 256; i += 1024) sh.mb1[i] = P.mb1[i];
  for (int i = tid; i < 512; i += 1024) sh.fb1[i] = P.fb1[i];
  if (tid < 128) {
    sh.mb2[tid]  = P.mb2[tid];  sh.fb2[tid]  = P.fb2[tid];
    sh.lnsw[tid] = P.lnsw[tid]; sh.lnsb[tid] = P.lnsb[tid];
    sh.lnmw[tid] = P.lnmw[tid]; sh.lnmb[tid] = P.lnmb[tid];
    sh.pl1w[tid] = P.pl1w[tid]; sh.pl1b[tid] = P.pl1b[tid];
    sh.pl2w[tid] = P.pl2w[tid]; sh.pl2b[tid] = P.pl2b[tid];
    sh.plfw[tid] = P.plfw[tid]; sh.plfb[tid] = P.plfb[tid];
  }
  {
    int kk = tid >> 7, s = tid & 127;
    float v = P.mu[s] + expf(P.lsig[s]) * P.noise[(b * 8 + kk) * 128 + s];
    sh.slots[kk][s] = v;
    sh.h16[kk][s] = (_Float16)v;
  }
  if (w >= 8) {   // zero pad rows 8..15 of a16/h16 (kept zero forever)
    sh.a16[w][lane] = (_Float16)0.f; sh.a16[w][lane + 64] = (_Float16)0.f;
    sh.h16[w][lane] = (_Float16)0.f; sh.h16[w][lane + 64] = (_Float16)0.f;
  }
  __syncthreads();

  for (int t = 0; t < 12; t++) {
    const _Float16* kt = P.kbuf + ((size_t)(b * 12 + t)) * 1024 * 128 + (size_t)n0 * 128;
    const _Float16* vt = P.vT   + ((size_t)(b * 12 + t)) * 128 * 1024 + n0;
    // ---- stage k~/v slice into LDS (32 KB each); single sync
    {
      int r = tid >> 4, c8 = (tid & 15) * 8;
      #pragma unroll
      for (int p = 0; p < 2; p++) {
        int row = p * 64 + r;
        *(half8*)&sh.k_lds[row][c8] = *(const half8*)(kt + (size_t)row * 128 + c8);
        *(half8*)&sh.v_lds[row][c8] = *(const half8*)(vt + (size_t)row * 1024 + c8);
      }
    }
    __syncthreads();

    for (int it = 0; it < 3; it++) {
      const int par = (t * 3 + it) & 1;
      float* updg = P.upd_p + ((size_t)(par * 16 + b) * 8 + g) * 1152;
      float* colg = P.col_p + ((size_t)(par * 16 + b) * 8 + g) * 64;
      // ---- ph1: w<8: LN_s(slots)->a16 rows 0..7 ; w>=8: gh (3 tiles each)
      if (w < 8) {
        float x0 = sh.slots[w][lane], x1 = sh.slots[w][lane + 64];
        float s = x0 + x1, sq = x0 * x0 + x1 * x1;
        #pragma unroll
        for (int m = 1; m < 64; m <<= 1) { s += __shfl_xor(s, m); sq += __shfl_xor(sq, m); }
        float mn = s * 0.0078125f;
        float vr = sq * 0.0078125f - mn * mn;
        float rs = rsqrtf(vr + 1e-5f);
        sh.a16[w][lane]      = (_Float16)((x0 - mn) * rs * sh.lnsw[lane]      + sh.lnsb[lane]);
        sh.a16[w][lane + 64] = (_Float16)((x1 - mn) * rs * sh.lnsw[lane + 64] + sh.lnsb[lane + 64]);
      } else {
        const int idx8 = w - 8;
        const _Float16* ar = &sh.h16[l15][quad * 8];
        #pragma unroll
        for (int tt = 0; tt < 3; tt++) {
          int ct = idx8 + tt * 8;
          const _Float16* Bg = P.Whh + (size_t)(ct * 16 + l15) * 128 + quad * 8;
          floatx4 acc = (floatx4){0.f, 0.f, 0.f, 0.f};
          #pragma unroll
          for (int ks = 0; ks < 4; ks++)
            acc = MFMA_F16(*(const half8*)(ar + ks * 32), *(const half8*)(Bg + ks * 32), acc);
          int col = ct * 16 + l15;
          #pragma unroll
          for (int r = 0; r < 4; r++) {
            int slot = quad * 4 + r;
            if (slot < 8) sh.gh[slot][col] = acc[r] + sh.bhh[col];
          }
        }
      }
      __syncthreads();
      // ---- ph2: ALL 16 waves: logits (dup MFMA per pair), softmax on 2 r's
      {
        int nloc0 = (w & 7) * 16;
        int rhalf = w >> 3;
        floatx4 acc = (floatx4){0.f, 0.f, 0.f, 0.f};
        const _Float16* ar = &sh.k_lds[nloc0 + l15][quad * 8];
        const _Float16* br = &sh.a16[l15][quad * 8];
        #pragma unroll
        for (int ks = 0; ks < 4; ks++)
          acc = MFMA_F16(*(const half8*)(ar + ks * 32), *(const half8*)(br + ks * 32), acc);
        float cs = 0.f;
        #pragma unroll
        for (int rr = 0; rr < 2; rr++) {
          int r = rhalf * 2 + rr;
          float v = (l15 < 8) ? acc[r] : -3.0e38f;
          float mx = v;
          mx = fmaxf(mx, __shfl_xor(mx, 1, 16));
          mx = fmaxf(mx, __shfl_xor(mx, 2, 16));
          mx = fmaxf(mx, __shfl_xor(mx, 4, 16));
          mx = fmaxf(mx, __shfl_xor(mx, 8, 16));
          float pv = (l15 < 8) ? expf(v - mx) : 0.f;
          float ss = pv;
          ss += __shfl_xor(ss, 1, 16); ss += __shfl_xor(ss, 2, 16);
          ss += __shfl_xor(ss, 4, 16); ss += __shfl_xor(ss, 8, 16);
          float pn = pv / ss;
          cs += pn;
          int nloc = nloc0 + quad * 4 + r;
          sh.u.sa.attnT[l15][nloc] = (l15 == 8) ? (_Float16)1.f : (_Float16)pn;
          if (it == 2 && l15 < 8)
            P.out_attn[((size_t)(b * 12 + t) * 1024 + n0 + nloc) * 8 + l15] = pn;
        }
        cs += __shfl_xor(cs, 16); cs += __shfl_xor(cs, 32);
        if (lane < 8) sh.u.sa.wcs[w][lane] = cs;
      }
      __syncthreads();
      // ---- ph3: w<8: updates = P^T @ v (row8 = local vsum) -> global
      if (w < 8) {
        floatx4 acc = (floatx4){0.f, 0.f, 0.f, 0.f};
        const _Float16* ar = &sh.u.sa.attnT[l15][quad * 8];
        const _Float16* br = &sh.v_lds[w * 16 + l15][quad * 8];
        #pragma unroll
        for (int ks = 0; ks < 4; ks++)
          acc = MFMA_F16(*(const half8*)(ar + ks * 32), *(const half8*)(br + ks * 32), acc);
        int scol = w * 16 + l15;
        #pragma unroll
        for (int r = 0; r < 4; r++) {
          int row = quad * 4 + r;
          if (row < 9)
            __hip_atomic_store(&updg[row * 128 + scol], acc[r],
                               __ATOMIC_RELAXED, __HIP_MEMORY_SCOPE_AGENT);
        }
      }
      if (tid < 8) {
        float c = 0.f;
        #pragma unroll
        for (int ww = 0; ww < 16; ww++) c += sh.u.sa.wcs[ww][tid];
        __hip_atomic_store(&colg[tid], c, __ATOMIC_RELAXED, __HIP_MEMORY_SCOPE_AGENT);
      }
      // ---- 8-block barrier (padded counter)
      bar_phase++;
      group_barrier(ctrb, 8 * bar_phase);
      // ---- ph4: reduce partials -> a16 rows 0..7 (vsum = row 8; no syncs)
      {
        int slot = tid >> 7, scol = tid & 127;
        const float* upb = P.upd_p + (size_t)(par * 16 + b) * 8 * 1152;
        float sum = 0.f, vs = 0.f;
        #pragma unroll
        for (int gg = 0; gg < 8; gg++) {
          sum += __hip_atomic_load((float*)(upb + gg * 1152 + slot * 128 + scol),
                                   __ATOMIC_RELAXED, __HIP_MEMORY_SCOPE_AGENT);
          vs  += __hip_atomic_load((float*)(upb + gg * 1152 + 8 * 128 + scol),
                                   __ATOMIC_RELAXED, __HIP_MEMORY_SCOPE_AGENT);
        }
        const float* cpb = P.col_p + (size_t)(par * 16 + b) * 8 * 64;
        float csum = 0.f;
        #pragma unroll
        for (int gg = 0; gg < 8; gg++)
          csum += __hip_atomic_load((float*)(cpb + gg * 64 + slot),
                                    __ATOMIC_RELAXED, __HIP_MEMORY_SCOPE_AGENT);
        float upd = (sum + 1e-8f * vs) / (csum + 1024.f * 1e-8f);
        sh.a16[slot][scol] = (_Float16)upd;
      }
      __syncthreads();
      // ---- ph5: gi (3 tiles in-register) + GRU gates fused (waves 0-7)
      if (w < 8) {
        const _Float16* ar = &sh.a16[l15][quad * 8];
        const _Float16* B0 = P.Wih + (size_t)(w * 16 + l15) * 128 + quad * 8;
        const _Float16* B1 = P.Wih + (size_t)((w + 8) * 16 + l15) * 128 + quad * 8;
        const _Float16* B2 = P.Wih + (size_t)((w + 16) * 16 + l15) * 128 + quad * 8;
        floatx4 ac = (floatx4){0.f, 0.f, 0.f, 0.f};
        floatx4 az = (floatx4){0.f, 0.f, 0.f, 0.f};
        floatx4 an = (floatx4){0.f, 0.f, 0.f, 0.f};
        #pragma unroll
        for (int ks = 0; ks < 4; ks++) {
          half8 af = *(const half8*)(ar + ks * 32);
          ac = MFMA_F16(af, *(const half8*)(B0 + ks * 32), ac);
          az = MFMA_F16(af, *(const half8*)(B1 + ks * 32), az);
          an = MFMA_F16(af, *(const half8*)(B2 + ks * 32), an);
        }
        int col = w * 16 + l15;
        #pragma unroll
        for (int r = 0; r < 4; r++) {
          int slot = quad * 4 + r;
          if (slot < 8) {
            float gic = ac[r] + sh.bih[col];
            float giz = az[r] + sh.bih[128 + col];
            float gin = an[r] + sh.bih[256 + col];
            float rg = 1.f / (1.f + expf(-(gic + sh.gh[slot][col])));
            float zg = 1.f / (1.f + expf(-(giz + sh.gh[slot][128 + col])));
            float ng = tanhf(gin + rg * sh.gh[slot][256 + col]);
            float h = sh.slots[slot][col];
            float x = (1.f - zg) * ng + zg * h;
            sh.slots[slot][col] = x;
            if (it == 2)
              P.out_slots[((size_t)(b * 12 + t) * 8 + slot) * 128 + col] = x;
          }
        }
      }
      __syncthreads();
      // ---- ph6: LN (lnm for MLP iters, pl1 for predictor entry) -> a16
      ln_to_a16(&sh, sh.slots, (it < 2) ? sh.lnmw : sh.pl1w,
                (it < 2) ? sh.lnmb : sh.pl1b, w, lane);
      __syncthreads();
      // ---- residual MLP (iters 0,1)
      if (it < 2) {
        {
          floatx4 acc = (floatx4){0.f, 0.f, 0.f, 0.f};
          const _Float16* ar = &sh.a16[l15][quad * 8];
          const _Float16* br = P.W1T + (size_t)(w * 16 + l15) * 128 + quad * 8;
          #pragma unroll
          for (int ks = 0; ks < 4; ks++)
            acc = MFMA_F16(*(const half8*)(ar + ks * 32), *(const half8*)(br + ks * 32), acc);
          int col = w * 16 + l15;
          #pragma unroll
          for (int r = 0; r < 4; r++) {
            int slot = quad * 4 + r;
            if (slot < 8) sh.u.mlp.m16[slot][col] = (_Float16)fmaxf(acc[r] + sh.mb1[col], 0.f);
            else          sh.u.mlp.m16[slot][col] = (_Float16)0.f;
          }
        }
        __syncthreads();
        if (w < 8) {   // MLP2 + residual; refresh h16 (GRU h-input next iter)
          floatx4 acc = (floatx4){0.f, 0.f, 0.f, 0.f};
          const _Float16* ar = &sh.u.mlp.m16[l15][quad * 8];
          const _Float16* br = P.W2T + (size_t)(w * 16 + l15) * 256 + quad * 8;
          #pragma unroll
          for (int ks = 0; ks < 8; ks++)
            acc = MFMA_F16(*(const half8*)(ar + ks * 32), *(const half8*)(br + ks * 32), acc);
          int col = w * 16 + l15;
          #pragma unroll
          for (int r = 0; r < 4; r++) {
            int slot = quad * 4 + r;
            if (slot < 8) {
              float ns = sh.slots[slot][col] + acc[r] + sh.mb2[col];
              sh.slots[slot][col] = ns;
              sh.h16[slot][col] = (_Float16)ns;
            }
          }
        }
        __syncthreads();
      }
    } // it

    // ---- predictor (redundant, identical in all 8 blocks); a16 = LN_pl1
    {
      const _Float16* ar = &sh.a16[l15][quad * 8];
      int gg = w >> 3, ct = w & 7, col = ct * 16 + l15;
      const _Float16* Bg = (gg == 0 ? P.pQT : P.pKT) + (size_t)(ct * 16 + l15) * 128 + quad * 8;
      floatx4 acc = (floatx4){0.f, 0.f, 0.f, 0.f};
      #pragma unroll
      for (int ks = 0; ks < 4; ks++)
        acc = MFMA_F16(*(const half8*)(ar + ks * 32), *(const half8*)(Bg + ks * 32), acc);
      float scale = (gg == 0) ? 0.17677669529663687f : 1.f;
      float* dst = (gg == 0) ? &sh.u.mha.qh[0][0] : &sh.u.mha.kh[0][0];
      #pragma unroll
      for (int r = 0; r < 4; r++) {
        int slot = quad * 4 + r;
        if (slot < 8) dst[slot * 128 + col] = acc[r] * scale;
      }
      if (w < 8) {
        const _Float16* Bg2 = P.pVT + (size_t)(w * 16 + l15) * 128 + quad * 8;
        floatx4 a2 = (floatx4){0.f, 0.f, 0.f, 0.f};
        #pragma unroll
        for (int ks = 0; ks < 4; ks++)
          a2 = MFMA_F16(*(const half8*)(ar + ks * 32), *(const half8*)(Bg2 + ks * 32), a2);
        int colv = w * 16 + l15;
        #pragma unroll
        for (int r = 0; r < 4; r++) {
          int slot = quad * 4 + r;
          if (slot < 8) sh.u.mha.vh[slot][colv] = a2[r];
        }
      }
    }
    __syncthreads();
    // ---- fused mha: scores + softmax + P@V, one wave per head (w<4)
    if (w < 4) {
      int h = w, a = lane >> 3, b2 = lane & 7;
      const float* qr = &sh.u.mha.qh[a][h * 32];
      const float* kr = &sh.u.mha.kh[b2][h * 32];
      float s = 0.f;
      #pragma unroll
      for (int d = 0; d < 32; d++) s += qr[d] * kr[d];
      float mx = s;
      mx = fmaxf(mx, __shfl_xor(mx, 1, 8));
      mx = fmaxf(mx, __shfl_xor(mx, 2, 8));
      mx = fmaxf(mx, __shfl_xor(mx, 4, 8));
      float e = expf(s - mx);
      float ssum = e;
      ssum += __shfl_xor(ssum, 1, 8); ssum += __shfl_xor(ssum, 2, 8); ssum += __shfl_xor(ssum, 4, 8);
      float p = e / ssum;
      float o0 = 0.f, o1 = 0.f, o2 = 0.f, o3 = 0.f;
      int d0 = h * 32 + b2 * 4;
      #pragma unroll
      for (int j = 0; j < 8; j++) {
        float pj = __shfl(p, (a << 3) + j);
        const float* vr = &sh.u.mha.vh[j][d0];
        o0 += pj * vr[0]; o1 += pj * vr[1]; o2 += pj * vr[2]; o3 += pj * vr[3];
      }
      sh.a16[a][d0]     = (_Float16)o0;
      sh.a16[a][d0 + 1] = (_Float16)o1;
      sh.a16[a][d0 + 2] = (_Float16)o2;
      sh.a16[a][d0 + 3] = (_Float16)o3;
    }
    __syncthreads();
    if (w < 8) {       // s += o @ Wo
      floatx4 acc = (floatx4){0.f, 0.f, 0.f, 0.f};
      const _Float16* ar = &sh.a16[l15][quad * 8];
      const _Float16* br = P.pOT + (size_t)(w * 16 + l15) * 128 + quad * 8;
      #pragma unroll
      for (int ks = 0; ks < 4; ks++)
        acc = MFMA_F16(*(const half8*)(ar + ks * 32), *(const half8*)(br + ks * 32), acc);
      int col = w * 16 + l15;
      #pragma unroll
      for (int r = 0; r < 4; r++) {
        int slot = quad * 4 + r;
        if (slot < 8) sh.slots[slot][col] += acc[r];
      }
    }
    __syncthreads();
    ln_to_a16(&sh, sh.slots, sh.pl2w, sh.pl2b, w, lane);
    __syncthreads();
    for (int ct = w; ct < 32; ct += 16) {   // FFN1 + relu
      floatx4 acc = (floatx4){0.f, 0.f, 0.f, 0.f};
      const _Float16* ar = &sh.a16[l15][quad * 8];
      const _Float16* br = P.pF1T + (size_t)(ct * 16 + l15) * 128 + quad * 8;
      #pragma unroll
      for (int ks = 0; ks < 4; ks++)
        acc = MFMA_F16(*(const half8*)(ar + ks * 32), *(const half8*)(br + ks * 32), acc);
      int col = ct * 16 + l15;
      #pragma unroll
      for (int r = 0; r < 4; r++) {
        int slot = quad * 4 + r;
        if (slot < 8) sh.u.ffn.f16[slot][col] = (_Float16)fmaxf(acc[r] + sh.fb1[col], 0.f);
        else          sh.u.ffn.f16[slot][col] = (_Float16)0.f;
      }
    }
    __syncthreads();
    if (w < 8) {       // FFN2 + residual
      floatx4 acc = (floatx4){0.f, 0.f, 0.f, 0.f};
      const _Float16* ar = &sh.u.ffn.f16[l15][quad * 8];
      const _Float16* br = P.pF2T + (size_t)(w * 16 + l15) * 512 + quad * 8;
      #pragma unroll 4
      for (int ks = 0; ks < 16; ks++)
        acc = MFMA_F16(*(const half8*)(ar + ks * 32), *(const half8*)(br + ks * 32), acc);
      int col = w * 16 + l15;
      #pragma unroll
      for (int r = 0; r < 4; r++) {
        int slot = quad * 4 + r;
        if (slot < 8) sh.slots[slot][col] += acc[r] + sh.fb2[col];
      }
    }
    __syncthreads();
    if (w < 8) {       // final LN -> carry; refresh h16 for next t
      float x0 = sh.slots[w][lane], x1 = sh.slots[w][lane + 64];
      float s = x0 + x1, sq = x0 * x0 + x1 * x1;
      #pragma unroll
      for (int m = 1; m < 64; m <<= 1) { s += __shfl_xor(s, m); sq += __shfl_xor(sq, m); }
      float mn = s * 0.0078125f;
      float vr = sq * 0.0078125f - mn * mn;
      float rs = rsqrtf(vr + 1e-5f);
      float y0 = (x0 - mn) * rs * sh.plfw[lane]      + sh.plfb[lane];
      float y1 = (x1 - mn) * rs * sh.plfw[lane + 64] + sh.plfb[lane + 64];
      sh.slots[w][lane] = y0;      sh.slots[w][lane + 64] = y1;
      sh.h16[w][lane] = (_Float16)y0; sh.h16[w][lane + 64] = (_Float16)y1;
    }
    __syncthreads();
  } // t
}

// ---------------------------------------------------------------------------
extern "C" void kernel_launch(void* const* d_in, const int* in_sizes, int n_in,
                              void* d_out, int out_size, void* d_ws, size_t ws_size,
                              hipStream_t stream) {
  const float* inp   = (const float*)d_in[0];
  const float* noise = (const float*)d_in[1];
  const float* mu    = (const float*)d_in[2];
  const float* lsig  = (const float*)d_in[3];
  const float* lniw  = (const float*)d_in[4];
  const float* lnib  = (const float*)d_in[5];
  const float* lnsw  = (const float*)d_in[6];
  const float* lnsb  = (const float*)d_in[7];
  const float* lnmw  = (const float*)d_in[8];
  const float* lnmb  = (const float*)d_in[9];
  const float* Wq    = (const float*)d_in[10];
  const float* Wk    = (const float*)d_in[11];
  const float* Wv    = (const float*)d_in[12];
  const float* gWih  = (const float*)d_in[13];
  const float* gWhh  = (const float*)d_in[14];
  const float* gbih  = (const float*)d_in[15];
  const float* gbhh  = (const float*)d_in[16];
  const float* mW1   = (const float*)d_in[17];
  const float* mb1   = (const float*)d_in[18];
  const float* mW2   = (const float*)d_in[19];
  const float* mb2   = (const float*)d_in[20];
  const float* pl1w  = (const float*)d_in[21];
  const float* pl1b  = (const float*)d_in[22];
  const float* pWq   = (const float*)d_in[23];
  const float* pWk   = (const float*)d_in[24];
  const float* pWv   = (const float*)d_in[25];
  const float* pWo   = (const float*)d_in[26];
  const float* pl2w  = (const float*)d_in[27];
  const float* pl2b  = (const float*)d_in[28];
  const float* pf1   = (const float*)d_in[29];
  const float* pfb1  = (const float*)d_in[30];
  const float* pf2   = (const float*)d_in[31];
  const float* pfb2  = (const float*)d_in[32];
  const float* plfw  = (const float*)d_in[33];
  const float* plfb  = (const float*)d_in[34];

  // workspace layout (f16 elements)
  _Float16* p   = (_Float16*)d_ws;
  _Float16* kbuf = p;  p += 25165824;
  _Float16* vT   = p;  p += 25165824;
  _Float16* WT   = p;  p += 65536;
  _Float16* Wih  = p;  p += 49152;
  _Float16* Whh  = p;  p += 49152;
  _Float16* W1T  = p;  p += 32768;
  _Float16* W2T  = p;  p += 32768;
  _Float16* pQT  = p;  p += 16384;
  _Float16* pKT  = p;  p += 16384;
  _Float16* pVT  = p;  p += 16384;
  _Float16* pOT  = p;  p += 16384;
  _Float16* pF1T = p;  p += 65536;
  _Float16* pF2T = p;  p += 65536;
  float* fb   = (float*)p;
  float* upd_p = fb;  fb += 2 * 16 * 8 * 1152;   // 294912
  float* col_p = fb;  fb += 2 * 16 * 8 * 64;     // 16384 (256B-padded groups)
  int*   ctr   = (int*)fb;                       // 16 x 64 (256B-padded)

  const float kscale = 0.08838834764831845f;  // S^-0.5, S=128
  init_ctr_kernel<<<1, 1024, 0, stream>>>(ctr);

  PrepJobs J;
  const float* srcs[11] = {Wv, gWih, gWhh, mW1, mW2, pWq, pWk, pWv, pWo, pf1, pf2};
  _Float16* dsts[11]    = {WT + 32768, Wih, Whh, W1T, W2T, pQT, pKT, pVT, pOT, pF1T, pF2T};
  int Ins[11]    = {256, 49152, 49152, 128, 256, 128, 128, 128, 128, 128, 512};
  int Outs[11]   = {128, 1, 1, 256, 128, 128, 128, 128, 128, 512, 128};
  int elemss[11] = {32768, 49152, 49152, 32768, 32768, 16384, 16384, 16384, 16384, 65536, 65536};
  int doTs[11]   = {1, 0, 0, 1, 1, 1, 1, 1, 1, 1, 1};
  float scales[11] = {1.f, 1.f, 1.f, 1.f, 1.f, 1.f, 1.f, 1.f, 1.f, 1.f, 1.f};
  for (int j = 0; j < 11; j++) {
    J.src[j] = srcs[j]; J.dst[j] = dsts[j]; J.In[j] = Ins[j]; J.Out[j] = Outs[j];
    J.elems[j] = elemss[j]; J.doT[j] = doTs[j]; J.scale[j] = scales[j];
  }
  dim3 gp(256, 11, 1);
  prep_all_kernel<<<gp, 256, 0, stream>>>(J);
  prep_wtilde_kernel<<<128, 256, 0, stream>>>(Wk, Wq, WT, kscale);

  dim3 g1(1536, 2, 1);
  gemm_kv_kernel<<<g1, 256, 0, stream>>>(inp, lniw, lnib, WT, kbuf, vT);

  P2Args a;
  a.kbuf = kbuf; a.vT = vT;
  a.Wih = Wih; a.Whh = Whh; a.W1T = W1T; a.W2T = W2T;
  a.pQT = pQT; a.pKT = pKT; a.pVT = pVT; a.pOT = pOT; a.pF1T = pF1T; a.pF2T = pF2T;
  a.noise = noise; a.mu = mu; a.lsig = lsig;
  a.lnsw = lnsw; a.lnsb = lnsb; a.lnmw = lnmw; a.lnmb = lnmb;
  a.bih = gbih; a.bhh = gbhh; a.mb1 = mb1; a.mb2 = mb2;
  a.pl1w = pl1w; a.pl1b = pl1b; a.pl2w = pl2w; a.pl2b = pl2b;
  a.fb1 = pfb1; a.fb2 = pfb2; a.plfw = plfw; a.plfb = plfb;
  a.out_slots = (float*)d_out;
  a.out_attn  = (float*)d_out + 196608;
  a.upd_p = upd_p; a.col_p = col_p; a.ctr = ctr;

  slot_attn_kernel<<<128, 1024, 0, stream>>>(a);
}

// Round 9
// 1325.117 us; speedup vs baseline: 1.4461x; 1.0482x over previous
//
#include <hip/hip_runtime.h>
#include <hip/hip_bf16.h>

typedef _Float16 half8 __attribute__((ext_vector_type(8)));
typedef float floatx4 __attribute__((ext_vector_type(4)));

#define MFMA_F16(a, b, c) __builtin_amdgcn_mfma_f32_16x16x32_f16((a), (b), (c), 0, 0, 0)

// ---------------------------------------------------------------------------
// fused prep: 11 f32->f16 (optional transpose, scale) jobs in one launch.
// ---------------------------------------------------------------------------
struct PrepJobs {
  const float* src[11];
  _Float16* dst[11];
  int In[11], Out[11], elems[11], doT[11];
  float scale[11];
};

__global__ void prep_all_kernel(PrepJobs J) {
  int j = blockIdx.y;
  int idx = blockIdx.x * 256 + threadIdx.x;
  if (idx >= J.elems[j]) return;
  float v;
  if (J.doT[j]) { int o = idx / J.In[j], i = idx - o * J.In[j]; v = J.src[j][i * J.Out[j] + o]; }
  else          { v = J.src[j][idx]; }
  J.dst[j][idx] = (_Float16)(v * J.scale[j]);
}

// W~T[s][i] = kscale * sum_o Wk[i][o] * Wq[s][o]   (folds Wq into the k GEMM)
__global__ void prep_wtilde_kernel(const float* __restrict__ Wk, const float* __restrict__ Wq,
                                   _Float16* __restrict__ WT, float scale) {
  int idx = blockIdx.x * 256 + threadIdx.x;   // 32768 = 128 s * 256 i
  int s = idx >> 8, i = idx & 255;
  const float* wk = Wk + (size_t)i * 128;
  const float* wq = Wq + (size_t)s * 128;
  float acc = 0.f;
  #pragma unroll 4
  for (int o = 0; o < 128; o++) acc += wk[o] * wq[o];
  WT[idx] = (_Float16)(acc * scale);
}

__global__ void init_ctr_kernel(int* __restrict__ ctr) {
  ctr[threadIdx.x] = 0;   // 1024 ints (16 batches x 64-int stride = 256B pad)
}

// ---------------------------------------------------------------------------
// phase 1: fused LN + dual GEMM.  grid (1536, 2), 256 threads. (unchanged)
// ---------------------------------------------------------------------------
__global__ __launch_bounds__(256) void gemm_kv_kernel(
    const float* __restrict__ x, const float* __restrict__ lnw_g,
    const float* __restrict__ lnb_g, const _Float16* __restrict__ WT,
    _Float16* __restrict__ kout, _Float16* __restrict__ vTout) {
  __shared__ union {
    struct { _Float16 A[128][72]; _Float16 B[128][72]; } s;
    _Float16 C[128][136];
  } u;
  __shared__ float s_mean[128], s_rstd[128], s_red[256][2], s_lnw[256], s_lnb[256];

  const int tid = threadIdx.x;
  const int bx = blockIdx.x, y = blockIdx.y;
  const size_t r0 = (size_t)bx * 128;
  const int w = tid >> 6, lane = tid & 63, quad = lane >> 4, l15 = lane & 15;

  s_lnw[tid] = lnw_g[tid];
  s_lnb[tid] = lnb_g[tid];
  {
    int row = tid >> 1, half = tid & 1;
    const float* p = x + (r0 + row) * 256 + half * 128;
    float s = 0.f, sq = 0.f;
    for (int i = 0; i < 32; i++) {
      float4 d = ((const float4*)p)[i];
      s += d.x + d.y + d.z + d.w;
      sq += d.x * d.x + d.y * d.y + d.z * d.z + d.w * d.w;
    }
    s_red[tid][0] = s; s_red[tid][1] = sq;
  }
  __syncthreads();
  if (tid < 128) {
    float s  = s_red[2 * tid][0] + s_red[2 * tid + 1][0];
    float sq = s_red[2 * tid][1] + s_red[2 * tid + 1][1];
    float m = s * (1.f / 256.f);
    float v = sq * (1.f / 256.f) - m * m;
    s_mean[tid] = m; s_rstd[tid] = rsqrtf(v + 1e-5f);
  }

  floatx4 acc[2][8];
  for (int rt = 0; rt < 2; rt++)
    for (int ct = 0; ct < 8; ct++) acc[rt][ct] = (floatx4){0.f, 0.f, 0.f, 0.f};

  for (int c = 0; c < 4; c++) {
    __syncthreads();
    for (int i = 0; i < 4; i++) {
      int g = tid + 256 * i;
      int row = g >> 3, c8 = g & 7;
      int col0 = c * 64 + c8 * 8;
      const float* p = x + (r0 + row) * 256 + col0;
      float4 d0 = ((const float4*)p)[0];
      float4 d1 = ((const float4*)p)[1];
      float f[8] = {d0.x, d0.y, d0.z, d0.w, d1.x, d1.y, d1.z, d1.w};
      float m = s_mean[row], rs = s_rstd[row];
      half8 hv;
      #pragma unroll
      for (int j = 0; j < 8; j++)
        hv[j] = (_Float16)((f[j] - m) * rs * s_lnw[col0 + j] + s_lnb[col0 + j]);
      *(half8*)&u.s.A[row][c8 * 8] = hv;
      *(half8*)&u.s.B[row][c8 * 8] = *(const half8*)(WT + (size_t)(y * 128 + row) * 256 + col0);
    }
    __syncthreads();
    #pragma unroll
    for (int ks = 0; ks < 2; ks++) {
      half8 af[2];
      af[0] = *(const half8*)&u.s.A[(2 * w) * 16 + l15][ks * 32 + quad * 8];
      af[1] = *(const half8*)&u.s.A[(2 * w + 1) * 16 + l15][ks * 32 + quad * 8];
      #pragma unroll
      for (int ct = 0; ct < 8; ct++) {
        half8 bf = *(const half8*)&u.s.B[ct * 16 + l15][ks * 32 + quad * 8];
        acc[0][ct] = MFMA_F16(af[0], bf, acc[0][ct]);
        acc[1][ct] = MFMA_F16(af[1], bf, acc[1][ct]);
      }
    }
  }

  const size_t bt = (size_t)(bx >> 3);
  const int n0loc = (bx & 7) * 128;
  if (y == 0) {
    for (int rt = 0; rt < 2; rt++)
      for (int ct = 0; ct < 8; ct++)
        #pragma unroll
        for (int r = 0; r < 4; r++) {
          size_t row = r0 + (2 * w + rt) * 16 + quad * 4 + r;
          kout[row * 128 + ct * 16 + l15] = (_Float16)acc[rt][ct][r];
        }
  } else {
    __syncthreads();
    for (int rt = 0; rt < 2; rt++)
      for (int ct = 0; ct < 8; ct++)
        #pragma unroll
        for (int r = 0; r < 4; r++)
          u.C[(2 * w + rt) * 16 + quad * 4 + r][ct * 16 + l15] = (_Float16)acc[rt][ct][r];
    __syncthreads();
    int s = tid >> 1, hf = tid & 1;
    for (int j = 0; j < 8; j++) {
      int nb = hf * 64 + j * 8;
      half8 tmp;
      #pragma unroll
      for (int e = 0; e < 8; e++) tmp[e] = u.C[nb + e][s];
      *(half8*)(vTout + (bt * 128 + s) * 1024 + n0loc + nb) = tmp;
    }
  }
}

// ---------------------------------------------------------------------------
// phase 2: slot-attention scan. grid 128 (= 16 batches x 8 n-groups), 1024 thr.
// Round-9 = R8 with the h16 race fixed (R8's correctness failure root cause):
//  - ph1 does NOT write h16 (waves 8-15 read h16 for gh in the SAME phase;
//    R8 wrote post-MLP slots into h16 there -> value-changing race).
//  - h16 protocol = R7's (verified passing): refreshed at MLP2 and final-LN
//    only, so it always equals slots at ph1 entry with no concurrent write.
// Kept from R8: row8-vsum trick + vsv register caching (vsum enters as
// 1e-8*vsv -> numerically incapable of the observed failure), 16-wave
// softmax, deterministic wcs colsum, deleted vsum prologue, R5-form gi.
// ---------------------------------------------------------------------------
struct P2Args {
  const _Float16 *kbuf, *vT;
  const _Float16 *Wih, *Whh, *W1T, *W2T;
  const _Float16 *pQT, *pKT, *pVT, *pOT, *pF1T, *pF2T;
  const float *noise, *mu, *lsig;
  const float *lnsw, *lnsb, *lnmw, *lnmb;
  const float *bih, *bhh, *mb1, *mb2;
  const float *pl1w, *pl1b, *pl2w, *pl2b, *fb1, *fb2, *plfw, *plfb;
  float *out_slots, *out_attn;
  float *upd_p;   // [2][16][8][9][128]
  float *col_p;   // [2][16][8][64]  (8 used, 256B padded)
  int   *ctr;     // [16][64]        (1 used, 256B padded)
};

struct SH {
  _Float16 k_lds[128][136];   // k~ slice [n_local][s]
  _Float16 v_lds[128][136];   // v slice [s][n_local]
  float slots[8][128];
  _Float16 a16[16][136];
  _Float16 h16[16][136];
  float gi[8][384];
  float gh[8][384];
  union {
    struct { _Float16 attnT[16][136]; float wcs[16][8]; } sa;
    struct { _Float16 m16[16][264]; } mlp;
    struct { float qh[8][128]; float kh[8][128]; float vh[8][128]; float sc[4][8][8]; } mha;
    struct { _Float16 f16[16][520]; } ffn;
  } u;
  float bih[384], bhh[384], mb1[256], mb2[128], fb1[512], fb2[128];
  float lnsw[128], lnsb[128], lnmw[128], lnmb[128];
  float pl1w[128], pl1b[128], pl2w[128], pl2b[128], plfw[128], plfb[128];
};

__device__ __forceinline__ void group_barrier(int* ctr, int target) {
  __syncthreads();   // drains vmcnt: all agent-scope stores complete
  if (threadIdx.x == 0) {
    __hip_atomic_fetch_add(ctr, 1, __ATOMIC_ACQ_REL, __HIP_MEMORY_SCOPE_AGENT);
    while (__hip_atomic_load(ctr, __ATOMIC_ACQUIRE, __HIP_MEMORY_SCOPE_AGENT) < target)
      __builtin_amdgcn_s_sleep(1);
  }
  __syncthreads();
}

__device__ __forceinline__ void ln_to_a16(SH* sh, const float (*src)[128],
                                          const float* wv, const float* bv,
                                          int w, int lane) {
  if (w < 8) {
    float x0 = src[w][lane], x1 = src[w][lane + 64];
    float s = x0 + x1, sq = x0 * x0 + x1 * x1;
    #pragma unroll
    for (int m = 1; m < 64; m <<= 1) { s += __shfl_xor(s, m); sq += __shfl_xor(sq, m); }
    float mn = s * 0.0078125f;
    float vr = sq * 0.0078125f - mn * mn;
    float rs = rsqrtf(vr + 1e-5f);
    sh->a16[w][lane]      = (_Float16)((x0 - mn) * rs * wv[lane]      + bv[lane]);
    sh->a16[w][lane + 64] = (_Float16)((x1 - mn) * rs * wv[lane + 64] + bv[lane + 64]);
  }
}

__global__ __launch_bounds__(1024, 4) void slot_attn_kernel(P2Args P) {
  __shared__ SH sh;
  const int tid = threadIdx.x;
  const int w = tid >> 6, lane = tid & 63, quad = lane >> 4, l15 = lane & 15;
  const int b = blockIdx.x & 15;       // batch
  const int g = blockIdx.x >> 4;       // n-group (0..7); same XCD for fixed b
  const int n0 = g * 128;
  int* ctrb = P.ctr + b * 64;          // 256B-padded counter
  int bar_phase = 0;

  for (int i = tid; i < 384; i += 1024) { sh.bih[i] = P.bih[i]; sh.bhh[i] = P.bhh[i]; }
  for (int i = tid; i < 256; i += 1024) sh.mb1[i] = P.mb1[i];
  for (int i = tid; i < 512; i += 1024) sh.fb1[i] = P.fb1[i];
  if (tid < 128) {
    sh.mb2[tid]  = P.mb2[tid];  sh.fb2[tid]  = P.fb2[tid];
    sh.lnsw[tid] = P.lnsw[tid]; sh.lnsb[tid] = P.lnsb[tid];
    sh.lnmw[tid] = P.lnmw[tid]; sh.lnmb[tid] = P.lnmb[tid];
    sh.pl1w[tid] = P.pl1w[tid]; sh.pl1b[tid] = P.pl1b[tid];
    sh.pl2w[tid] = P.pl2w[tid]; sh.pl2b[tid] = P.pl2b[tid];
    sh.plfw[tid] = P.plfw[tid]; sh.plfb[tid] = P.plfb[tid];
  }
  {
    int kk = tid >> 7, s = tid & 127;
    float v = P.mu[s] + expf(P.lsig[s]) * P.noise[(b * 8 + kk) * 128 + s];
    sh.slots[kk][s] = v;
    sh.h16[kk][s] = (_Float16)v;
  }
  if (w >= 8) {   // zero pad rows 8..15 of a16/h16 once (kept zero forever)
    sh.a16[w][lane] = (_Float16)0.f; sh.a16[w][lane + 64] = (_Float16)0.f;
    sh.h16[w][lane] = (_Float16)0.f; sh.h16[w][lane + 64] = (_Float16)0.f;
  }
  __syncthreads();

  for (int t = 0; t < 12; t++) {
    const _Float16* kt = P.kbuf + ((size_t)(b * 12 + t)) * 1024 * 128 + (size_t)n0 * 128;
    const _Float16* vt = P.vT   + ((size_t)(b * 12 + t)) * 128 * 1024 + n0;
    // ---- stage k~/v slice into LDS (32 KB each); single sync
    {
      int r = tid >> 4, c8 = (tid & 15) * 8;
      #pragma unroll
      for (int p = 0; p < 2; p++) {
        int row = p * 64 + r;
        *(half8*)&sh.k_lds[row][c8] = *(const half8*)(kt + (size_t)row * 128 + c8);
        *(half8*)&sh.v_lds[row][c8] = *(const half8*)(vt + (size_t)row * 1024 + c8);
      }
    }
    __syncthreads();

    float vsv = 0.f;   // per-t: Sigma_n v (row-8 partials, read once at it==0)

    for (int it = 0; it < 3; it++) {
      const int par = (t * 3 + it) & 1;
      float* updg = P.upd_p + ((size_t)(par * 16 + b) * 8 + g) * 1152;
      float* colg = P.col_p + ((size_t)(par * 16 + b) * 8 + g) * 64;
      // ---- ph1: w<8: LN_s(slots)->a16 ONLY (no h16 write — waves 8-15 are
      //           reading h16 for gh in this same phase); w>=8: gh (3 tiles)
      if (w < 8) {
        float x0 = sh.slots[w][lane], x1 = sh.slots[w][lane + 64];
        float s = x0 + x1, sq = x0 * x0 + x1 * x1;
        #pragma unroll
        for (int m = 1; m < 64; m <<= 1) { s += __shfl_xor(s, m); sq += __shfl_xor(sq, m); }
        float mn = s * 0.0078125f;
        float vr = sq * 0.0078125f - mn * mn;
        float rs = rsqrtf(vr + 1e-5f);
        sh.a16[w][lane]      = (_Float16)((x0 - mn) * rs * sh.lnsw[lane]      + sh.lnsb[lane]);
        sh.a16[w][lane + 64] = (_Float16)((x1 - mn) * rs * sh.lnsw[lane + 64] + sh.lnsb[lane + 64]);
      } else {
        const int idx8 = w - 8;
        const _Float16* ar = &sh.h16[l15][quad * 8];
        #pragma unroll
        for (int tt = 0; tt < 3; tt++) {
          int ct = idx8 + tt * 8;
          const _Float16* Bg = P.Whh + (size_t)(ct * 16 + l15) * 128 + quad * 8;
          floatx4 acc = (floatx4){0.f, 0.f, 0.f, 0.f};
          #pragma unroll
          for (int ks = 0; ks < 4; ks++)
            acc = MFMA_F16(*(const half8*)(ar + ks * 32), *(const half8*)(Bg + ks * 32), acc);
          int col = ct * 16 + l15;
          #pragma unroll
          for (int r = 0; r < 4; r++) {
            int slot = quad * 4 + r;
            if (slot < 8) sh.gh[slot][col] = acc[r] + sh.bhh[col];
          }
        }
      }
      __syncthreads();
      // ---- ph2: ALL 16 waves: logits (wave pairs dup the MFMA), softmax 2 r's
      {
        int nloc0 = (w & 7) * 16;
        int rhalf = w >> 3;
        floatx4 acc = (floatx4){0.f, 0.f, 0.f, 0.f};
        const _Float16* ar = &sh.k_lds[nloc0 + l15][quad * 8];
        const _Float16* br = &sh.a16[l15][quad * 8];
        #pragma unroll
        for (int ks = 0; ks < 4; ks++)
          acc = MFMA_F16(*(const half8*)(ar + ks * 32), *(const half8*)(br + ks * 32), acc);
        float cs = 0.f;
        #pragma unroll
        for (int rr = 0; rr < 2; rr++) {
          int r = rhalf * 2 + rr;
          float v = (l15 < 8) ? acc[r] : -3.0e38f;
          float mx = v;
          mx = fmaxf(mx, __shfl_xor(mx, 1, 16));
          mx = fmaxf(mx, __shfl_xor(mx, 2, 16));
          mx = fmaxf(mx, __shfl_xor(mx, 4, 16));
          mx = fmaxf(mx, __shfl_xor(mx, 8, 16));
          float pv = (l15 < 8) ? expf(v - mx) : 0.f;
          float ss = pv;
          ss += __shfl_xor(ss, 1, 16); ss += __shfl_xor(ss, 2, 16);
          ss += __shfl_xor(ss, 4, 16); ss += __shfl_xor(ss, 8, 16);
          float pn = pv / ss;
          cs += pn;
          int nloc = nloc0 + quad * 4 + r;
          sh.u.sa.attnT[l15][nloc] = (l15 == 8) ? (_Float16)1.f : (_Float16)pn;
          if (it == 2 && l15 < 8)
            P.out_attn[((size_t)(b * 12 + t) * 1024 + n0 + nloc) * 8 + l15] = pn;
        }
        cs += __shfl_xor(cs, 16); cs += __shfl_xor(cs, 32);
        if (lane < 8) sh.u.sa.wcs[w][lane] = cs;
      }
      __syncthreads();
      // ---- ph3: w<8: updates = P^T @ v (row8 = local vsum, free) -> global
      if (w < 8) {
        floatx4 acc = (floatx4){0.f, 0.f, 0.f, 0.f};
        const _Float16* ar = &sh.u.sa.attnT[l15][quad * 8];
        const _Float16* br = &sh.v_lds[w * 16 + l15][quad * 8];
        #pragma unroll
        for (int ks = 0; ks < 4; ks++)
          acc = MFMA_F16(*(const half8*)(ar + ks * 32), *(const half8*)(br + ks * 32), acc);
        int scol = w * 16 + l15;
        #pragma unroll
        for (int r = 0; r < 4; r++) {
          int row = quad * 4 + r;
          if (row < 9)
            __hip_atomic_store(&updg[row * 128 + scol], acc[r],
                               __ATOMIC_RELAXED, __HIP_MEMORY_SCOPE_AGENT);
        }
      }
      if (tid < 8) {
        float c = 0.f;
        #pragma unroll
        for (int ww = 0; ww < 16; ww++) c += sh.u.sa.wcs[ww][tid];
        __hip_atomic_store(&colg[tid], c, __ATOMIC_RELAXED, __HIP_MEMORY_SCOPE_AGENT);
      }
      // ---- 8-block barrier (padded counter)
      bar_phase++;
      group_barrier(ctrb, 8 * bar_phase);
      // ---- ph4: reduce partials -> a16 rows 0..7 (vsv register, it==0 only)
      {
        int slot = tid >> 7, scol = tid & 127;
        const float* upb = P.upd_p + (size_t)(par * 16 + b) * 8 * 1152;
        float sum = 0.f;
        #pragma unroll
        for (int gg = 0; gg < 8; gg++)
          sum += __hip_atomic_load((float*)(upb + gg * 1152 + slot * 128 + scol),
                                   __ATOMIC_RELAXED, __HIP_MEMORY_SCOPE_AGENT);
        const float* cpb = P.col_p + (size_t)(par * 16 + b) * 8 * 64;
        float csum = 0.f;
        #pragma unroll
        for (int gg = 0; gg < 8; gg++)
          csum += __hip_atomic_load((float*)(cpb + gg * 64 + slot),
                                    __ATOMIC_RELAXED, __HIP_MEMORY_SCOPE_AGENT);
        if (it == 0) {
          float vs = 0.f;
          #pragma unroll
          for (int gg = 0; gg < 8; gg++)
            vs += __hip_atomic_load((float*)(upb + gg * 1152 + 8 * 128 + scol),
                                    __ATOMIC_RELAXED, __HIP_MEMORY_SCOPE_AGENT);
          vsv = vs;
        }
        float upd = (sum + 1e-8f * vsv) / (csum + 1024.f * 1e-8f);
        sh.a16[slot][scol] = (_Float16)upd;
      }
      __syncthreads();
      // ---- ph5: GRU gi: all waves tile ct=w; w<8 also ct=16+w
      {
        const _Float16* ar = &sh.a16[l15][quad * 8];
        const _Float16* Bg = P.Wih + (size_t)(w * 16 + l15) * 128 + quad * 8;
        floatx4 acc = (floatx4){0.f, 0.f, 0.f, 0.f};
        #pragma unroll
        for (int ks = 0; ks < 4; ks++)
          acc = MFMA_F16(*(const half8*)(ar + ks * 32), *(const half8*)(Bg + ks * 32), acc);
        int col = w * 16 + l15;
        #pragma unroll
        for (int r = 0; r < 4; r++) {
          int slot = quad * 4 + r;
          if (slot < 8) sh.gi[slot][col] = acc[r] + sh.bih[col];
        }
        if (w < 8) {
          int col2 = (16 + w) * 16 + l15;
          const _Float16* Bg2 = P.Wih + (size_t)((16 + w) * 16 + l15) * 128 + quad * 8;
          floatx4 acc2 = (floatx4){0.f, 0.f, 0.f, 0.f};
          #pragma unroll
          for (int ks = 0; ks < 4; ks++)
            acc2 = MFMA_F16(*(const half8*)(ar + ks * 32), *(const half8*)(Bg2 + ks * 32), acc2);
          #pragma unroll
          for (int r = 0; r < 4; r++) {
            int slot = quad * 4 + r;
            if (slot < 8) sh.gi[slot][col2] = acc2[r] + sh.bih[col2];
          }
        }
      }
      __syncthreads();
      // ---- ph6: gates + LN fused (waves 0-7); writes slots + a16 (lnm / pl1)
      if (w < 8) {
        float h0 = sh.slots[w][lane], h1 = sh.slots[w][lane + 64];
        float r0 = 1.f / (1.f + expf(-(sh.gi[w][lane]       + sh.gh[w][lane])));
        float z0 = 1.f / (1.f + expf(-(sh.gi[w][128 + lane] + sh.gh[w][128 + lane])));
        float n0v = tanhf(sh.gi[w][256 + lane] + r0 * sh.gh[w][256 + lane]);
        float x0 = (1.f - z0) * n0v + z0 * h0;
        int l64 = lane + 64;
        float r1 = 1.f / (1.f + expf(-(sh.gi[w][l64]       + sh.gh[w][l64])));
        float z1 = 1.f / (1.f + expf(-(sh.gi[w][128 + l64] + sh.gh[w][128 + l64])));
        float n1v = tanhf(sh.gi[w][256 + l64] + r1 * sh.gh[w][256 + l64]);
        float x1 = (1.f - z1) * n1v + z1 * h1;
        sh.slots[w][lane] = x0; sh.slots[w][lane + 64] = x1;
        if (it == 2 && g == 0) {
          P.out_slots[((size_t)(b * 12 + t) * 8 + w) * 128 + lane]      = x0;
          P.out_slots[((size_t)(b * 12 + t) * 8 + w) * 128 + lane + 64] = x1;
        }
        const float* wv = (it < 2) ? sh.lnmw : sh.pl1w;
        const float* bv = (it < 2) ? sh.lnmb : sh.pl1b;
        float s = x0 + x1, sq = x0 * x0 + x1 * x1;
        #pragma unroll
        for (int m = 1; m < 64; m <<= 1) { s += __shfl_xor(s, m); sq += __shfl_xor(sq, m); }
        float mn = s * 0.0078125f;
        float vr = sq * 0.0078125f - mn * mn;
        float rs = rsqrtf(vr + 1e-5f);
        sh.a16[w][lane]      = (_Float16)((x0 - mn) * rs * wv[lane]      + bv[lane]);
        sh.a16[w][lane + 64] = (_Float16)((x1 - mn) * rs * wv[lane + 64] + bv[lane + 64]);
      }
      __syncthreads();
      // ---- residual MLP (iters 0,1)
      if (it < 2) {
        {
          floatx4 acc = (floatx4){0.f, 0.f, 0.f, 0.f};
          const _Float16* ar = &sh.a16[l15][quad * 8];
          const _Float16* br = P.W1T + (size_t)(w * 16 + l15) * 128 + quad * 8;
          #pragma unroll
          for (int ks = 0; ks < 4; ks++)
            acc = MFMA_F16(*(const half8*)(ar + ks * 32), *(const half8*)(br + ks * 32), acc);
          int col = w * 16 + l15;
          #pragma unroll
          for (int r = 0; r < 4; r++) {
            int slot = quad * 4 + r;
            if (slot < 8) sh.u.mlp.m16[slot][col] = (_Float16)fmaxf(acc[r] + sh.mb1[col], 0.f);
            else          sh.u.mlp.m16[slot][col] = (_Float16)0.f;
          }
        }
        __syncthreads();
        if (w < 8) {   // MLP2 + residual; refresh h16 (GRU h-input next iter)
          floatx4 acc = (floatx4){0.f, 0.f, 0.f, 0.f};
          const _Float16* ar = &sh.u.mlp.m16[l15][quad * 8];
          const _Float16* br = P.W2T + (size_t)(w * 16 + l15) * 256 + quad * 8;
          #pragma unroll
          for (int ks = 0; ks < 8; ks++)
            acc = MFMA_F16(*(const half8*)(ar + ks * 32), *(const half8*)(br + ks * 32), acc);
          int col = w * 16 + l15;
          #pragma unroll
          for (int r = 0; r < 4; r++) {
            int slot = quad * 4 + r;
            if (slot < 8) {
              float ns = sh.slots[slot][col] + acc[r] + sh.mb2[col];
              sh.slots[slot][col] = ns;
              sh.h16[slot][col] = (_Float16)ns;
            }
          }
        }
        __syncthreads();
      }
    } // it

    // ---- predictor (redundant, identical in all 8 blocks); a16 = LN_pl1
    {
      const _Float16* ar = &sh.a16[l15][quad * 8];
      int gg = w >> 3, ct = w & 7, col = ct * 16 + l15;
      const _Float16* Bg = (gg == 0 ? P.pQT : P.pKT) + (size_t)(ct * 16 + l15) * 128 + quad * 8;
      floatx4 acc = (floatx4){0.f, 0.f, 0.f, 0.f};
      #pragma unroll
      for (int ks = 0; ks < 4; ks++)
        acc = MFMA_F16(*(const half8*)(ar + ks * 32), *(const half8*)(Bg + ks * 32), acc);
      float scale = (gg == 0) ? 0.17677669529663687f : 1.f;
      float* dst = (gg == 0) ? &sh.u.mha.qh[0][0] : &sh.u.mha.kh[0][0];
      #pragma unroll
      for (int r = 0; r < 4; r++) {
        int slot = quad * 4 + r;
        if (slot < 8) dst[slot * 128 + col] = acc[r] * scale;
      }
      if (w < 8) {
        const _Float16* Bg2 = P.pVT + (size_t)(w * 16 + l15) * 128 + quad * 8;
        floatx4 a2 = (floatx4){0.f, 0.f, 0.f, 0.f};
        #pragma unroll
        for (int ks = 0; ks < 4; ks++)
          a2 = MFMA_F16(*(const half8*)(ar + ks * 32), *(const half8*)(Bg2 + ks * 32), a2);
        int colv = w * 16 + l15;
        #pragma unroll
        for (int r = 0; r < 4; r++) {
          int slot = quad * 4 + r;
          if (slot < 8) sh.u.mha.vh[slot][colv] = a2[r];
        }
      }
    }
    __syncthreads();
    // ---- fused mha: scores + softmax + P@V, one wave per head (w<4)
    if (w < 4) {
      int h = w, a = lane >> 3, b2 = lane & 7;
      const float* qr = &sh.u.mha.qh[a][h * 32];
      const float* kr = &sh.u.mha.kh[b2][h * 32];
      float s = 0.f;
      #pragma unroll
      for (int d = 0; d < 32; d++) s += qr[d] * kr[d];
      float mx = s;
      mx = fmaxf(mx, __shfl_xor(mx, 1, 8));
      mx = fmaxf(mx, __shfl_xor(mx, 2, 8));
      mx = fmaxf(mx, __shfl_xor(mx, 4, 8));
      float e = expf(s - mx);
      float ssum = e;
      ssum += __shfl_xor(ssum, 1, 8); ssum += __shfl_xor(ssum, 2, 8); ssum += __shfl_xor(ssum, 4, 8);
      float p = e / ssum;
      float o0 = 0.f, o1 = 0.f, o2 = 0.f, o3 = 0.f;
      int d0 = h * 32 + b2 * 4;
      #pragma unroll
      for (int j = 0; j < 8; j++) {
        float pj = __shfl(p, (a << 3) + j);
        const float* vr = &sh.u.mha.vh[j][d0];
        o0 += pj * vr[0]; o1 += pj * vr[1]; o2 += pj * vr[2]; o3 += pj * vr[3];
      }
      sh.a16[a][d0]     = (_Float16)o0;
      sh.a16[a][d0 + 1] = (_Float16)o1;
      sh.a16[a][d0 + 2] = (_Float16)o2;
      sh.a16[a][d0 + 3] = (_Float16)o3;
    }
    __syncthreads();
    if (w < 8) {       // s += o @ Wo
      floatx4 acc = (floatx4){0.f, 0.f, 0.f, 0.f};
      const _Float16* ar = &sh.a16[l15][quad * 8];
      const _Float16* br = P.pOT + (size_t)(w * 16 + l15) * 128 + quad * 8;
      #pragma unroll
      for (int ks = 0; ks < 4; ks++)
        acc = MFMA_F16(*(const half8*)(ar + ks * 32), *(const half8*)(br + ks * 32), acc);
      int col = w * 16 + l15;
      #pragma unroll
      for (int r = 0; r < 4; r++) {
        int slot = quad * 4 + r;
        if (slot < 8) sh.slots[slot][col] += acc[r];
      }
    }
    __syncthreads();
    ln_to_a16(&sh, sh.slots, sh.pl2w, sh.pl2b, w, lane);
    __syncthreads();
    for (int ct = w; ct < 32; ct += 16) {   // FFN1 + relu
      floatx4 acc = (floatx4){0.f, 0.f, 0.f, 0.f};
      const _Float16* ar = &sh.a16[l15][quad * 8];
      const _Float16* br = P.pF1T + (size_t)(ct * 16 + l15) * 128 + quad * 8;
      #pragma unroll
      for (int ks = 0; ks < 4; ks++)
        acc = MFMA_F16(*(const half8*)(ar + ks * 32), *(const half8*)(br + ks * 32), acc);
      int col = ct * 16 + l15;
      #pragma unroll
      for (int r = 0; r < 4; r++) {
        int slot = quad * 4 + r;
        if (slot < 8) sh.u.ffn.f16[slot][col] = (_Float16)fmaxf(acc[r] + sh.fb1[col], 0.f);
        else          sh.u.ffn.f16[slot][col] = (_Float16)0.f;
      }
    }
    __syncthreads();
    if (w < 8) {       // FFN2 + residual
      floatx4 acc = (floatx4){0.f, 0.f, 0.f, 0.f};
      const _Float16* ar = &sh.u.ffn.f16[l15][quad * 8];
      const _Float16* br = P.pF2T + (size_t)(w * 16 + l15) * 512 + quad * 8;
      #pragma unroll 4
      for (int ks = 0; ks < 16; ks++)
        acc = MFMA_F16(*(const half8*)(ar + ks * 32), *(const half8*)(br + ks * 32), acc);
      int col = w * 16 + l15;
      #pragma unroll
      for (int r = 0; r < 4; r++) {
        int slot = quad * 4 + r;
        if (slot < 8) sh.slots[slot][col] += acc[r] + sh.fb2[col];
      }
    }
    __syncthreads();
    if (w < 8) {       // final LN -> carry; refresh h16 for next t
      float x0 = sh.slots[w][lane], x1 = sh.slots[w][lane + 64];
      float s = x0 + x1, sq = x0 * x0 + x1 * x1;
      #pragma unroll
      for (int m = 1; m < 64; m <<= 1) { s += __shfl_xor(s, m); sq += __shfl_xor(sq, m); }
      float mn = s * 0.0078125f;
      float vr = sq * 0.0078125f - mn * mn;
      float rs = rsqrtf(vr + 1e-5f);
      float y0 = (x0 - mn) * rs * sh.plfw[lane]      + sh.plfb[lane];
      float y1 = (x1 - mn) * rs * sh.plfw[lane + 64] + sh.plfb[lane + 64];
      sh.slots[w][lane] = y0;      sh.slots[w][lane + 64] = y1;
      sh.h16[w][lane] = (_Float16)y0; sh.h16[w][lane + 64] = (_Float16)y1;
    }
    __syncthreads();
  } // t
}

// ---------------------------------------------------------------------------
extern "C" void kernel_launch(void* const* d_in, const int* in_sizes, int n_in,
                              void* d_out, int out_size, void* d_ws, size_t ws_size,
                              hipStream_t stream) {
  const float* inp   = (const float*)d_in[0];
  const float* noise = (const float*)d_in[1];
  const float* mu    = (const float*)d_in[2];
  const float* lsig  = (const float*)d_in[3];
  const float* lniw  = (const float*)d_in[4];
  const float* lnib  = (const float*)d_in[5];
  const float* lnsw  = (const float*)d_in[6];
  const float* lnsb  = (const float*)d_in[7];
  const float* lnmw  = (const float*)d_in[8];
  const float* lnmb  = (const float*)d_in[9];
  const float* Wq    = (const float*)d_in[10];
  const float* Wk    = (const float*)d_in[11];
  const float* Wv    = (const float*)d_in[12];
  const float* gWih  = (const float*)d_in[13];
  const float* gWhh  = (const float*)d_in[14];
  const float* gbih  = (const float*)d_in[15];
  const float* gbhh  = (const float*)d_in[16];
  const float* mW1   = (const float*)d_in[17];
  const float* mb1   = (const float*)d_in[18];
  const float* mW2   = (const float*)d_in[19];
  const float* mb2   = (const float*)d_in[20];
  const float* pl1w  = (const float*)d_in[21];
  const float* pl1b  = (const float*)d_in[22];
  const float* pWq   = (const float*)d_in[23];
  const float* pWk   = (const float*)d_in[24];
  const float* pWv   = (const float*)d_in[25];
  const float* pWo   = (const float*)d_in[26];
  const float* pl2w  = (const float*)d_in[27];
  const float* pl2b  = (const float*)d_in[28];
  const float* pf1   = (const float*)d_in[29];
  const float* pfb1  = (const float*)d_in[30];
  const float* pf2   = (const float*)d_in[31];
  const float* pfb2  = (const float*)d_in[32];
  const float* plfw  = (const float*)d_in[33];
  const float* plfb  = (const float*)d_in[34];

  // workspace layout (f16 elements)
  _Float16* p   = (_Float16*)d_ws;
  _Float16* kbuf = p;  p += 25165824;
  _Float16* vT   = p;  p += 25165824;
  _Float16* WT   = p;  p += 65536;
  _Float16* Wih  = p;  p += 49152;
  _Float16* Whh  = p;  p += 49152;
  _Float16* W1T  = p;  p += 32768;
  _Float16* W2T  = p;  p += 32768;
  _Float16* pQT  = p;  p += 16384;
  _Float16* pKT  = p;  p += 16384;
  _Float16* pVT  = p;  p += 16384;
  _Float16* pOT  = p;  p += 16384;
  _Float16* pF1T = p;  p += 65536;
  _Float16* pF2T = p;  p += 65536;
  float* fb   = (float*)p;
  float* upd_p = fb;  fb += 2 * 16 * 8 * 1152;   // 294912
  float* col_p = fb;  fb += 2 * 16 * 8 * 64;     // 16384 (256B-padded groups)
  int*   ctr   = (int*)fb;                       // 16 x 64 (256B-padded)

  const float kscale = 0.08838834764831845f;  // S^-0.5, S=128
  init_ctr_kernel<<<1, 1024, 0, stream>>>(ctr);

  PrepJobs J;
  const float* srcs[11] = {Wv, gWih, gWhh, mW1, mW2, pWq, pWk, pWv, pWo, pf1, pf2};
  _Float16* dsts[11]    = {WT + 32768, Wih, Whh, W1T, W2T, pQT, pKT, pVT, pOT, pF1T, pF2T};
  int Ins[11]    = {256, 49152, 49152, 128, 256, 128, 128, 128, 128, 128, 512};
  int Outs[11]   = {128, 1, 1, 256, 128, 128, 128, 128, 128, 512, 128};
  int elemss[11] = {32768, 49152, 49152, 32768, 32768, 16384, 16384, 16384, 16384, 65536, 65536};
  int doTs[11]   = {1, 0, 0, 1, 1, 1, 1, 1, 1, 1, 1};
  float scales[11] = {1.f, 1.f, 1.f, 1.f, 1.f, 1.f, 1.f, 1.f, 1.f, 1.f, 1.f};
  for (int j = 0; j < 11; j++) {
    J.src[j] = srcs[j]; J.dst[j] = dsts[j]; J.In[j] = Ins[j]; J.Out[j] = Outs[j];
    J.elems[j] = elemss[j]; J.doT[j] = doTs[j]; J.scale[j] = scales[j];
  }
  dim3 gp(256, 11, 1);
  prep_all_kernel<<<gp, 256, 0, stream>>>(J);
  prep_wtilde_kernel<<<128, 256, 0, stream>>>(Wk, Wq, WT, kscale);

  dim3 g1(1536, 2, 1);
  gemm_kv_kernel<<<g1, 256, 0, stream>>>(inp, lniw, lnib, WT, kbuf, vT);

  P2Args a;
  a.kbuf = kbuf; a.vT = vT;
  a.Wih = Wih; a.Whh = Whh; a.W1T = W1T; a.W2T = W2T;
  a.pQT = pQT; a.pKT = pKT; a.pVT = pVT; a.pOT = pOT; a.pF1T = pF1T; a.pF2T = pF2T;
  a.noise = noise; a.mu = mu; a.lsig = lsig;
  a.lnsw = lnsw; a.lnsb = lnsb; a.lnmw = lnmw; a.lnmb = lnmb;
  a.bih = gbih; a.bhh = gbhh; a.mb1 = mb1; a.mb2 = mb2;
  a.pl1w = pl1w; a.pl1b = pl1b; a.pl2w = pl2w; a.pl2b = pl2b;
  a.fb1 = pfb1; a.fb2 = pfb2; a.plfw = plfw; a.plfb = plfb;
  a.out_slots = (float*)d_out;
  a.out_attn  = (float*)d_out + 196608;
  a.upd_p = upd_p; a.col_p = col_p; a.ctr = ctr;

  slot_attn_kernel<<<128, 1024, 0, stream>>>(a);
}

// Round 12
// 1211.457 us; speedup vs baseline: 1.5818x; 1.0938x over previous
//
#include <hip/hip_runtime.h>
#include <hip/hip_bf16.h>

typedef _Float16 half8 __attribute__((ext_vector_type(8)));
typedef float floatx4 __attribute__((ext_vector_type(4)));

#define MFMA_F16(a, b, c) __builtin_amdgcn_mfma_f32_16x16x32_f16((a), (b), (c), 0, 0, 0)

// ---------------------------------------------------------------------------
// fused prep: 11 f32->f16 (optional transpose, scale) jobs in one launch.
// ---------------------------------------------------------------------------
struct PrepJobs {
  const float* src[11];
  _Float16* dst[11];
  int In[11], Out[11], elems[11], doT[11];
  float scale[11];
};

__global__ void prep_all_kernel(PrepJobs J) {
  int j = blockIdx.y;
  int idx = blockIdx.x * 256 + threadIdx.x;
  if (idx >= J.elems[j]) return;
  float v;
  if (J.doT[j]) { int o = idx / J.In[j], i = idx - o * J.In[j]; v = J.src[j][i * J.Out[j] + o]; }
  else          { v = J.src[j][idx]; }
  J.dst[j][idx] = (_Float16)(v * J.scale[j]);
}

// W~T[s][i] = kscale * sum_o Wk[i][o] * Wq[s][o]   (folds Wq into the k GEMM)
__global__ void prep_wtilde_kernel(const float* __restrict__ Wk, const float* __restrict__ Wq,
                                   _Float16* __restrict__ WT, float scale) {
  int idx = blockIdx.x * 256 + threadIdx.x;   // 32768 = 128 s * 256 i
  int s = idx >> 8, i = idx & 255;
  const float* wk = Wk + (size_t)i * 128;
  const float* wq = Wq + (size_t)s * 128;
  float acc = 0.f;
  #pragma unroll 4
  for (int o = 0; o < 128; o++) acc += wk[o] * wq[o];
  WT[idx] = (_Float16)(acc * scale);
}

__global__ void init_ctr_kernel(int* __restrict__ ctr) {
  ctr[threadIdx.x] = 0;   // 1024 ints (16 batches x 64-int stride = 256B pad)
}

// ---------------------------------------------------------------------------
// phase 1: fused LN + dual GEMM, single-pass over x. grid 1536, 256 threads.
// R10: the two y-blocks are fused — stats once, A-stage once, BOTH B-halves
// per chunk (B0 = k~ weights, B1 = v weights), dual accumulators. x is read
// 2x total (stats + GEMM) instead of 4x: saves ~400 MB of HBM traffic.
// ---------------------------------------------------------------------------
__global__ __launch_bounds__(256) void gemm_kv_kernel(
    const float* __restrict__ x, const float* __restrict__ lnw_g,
    const float* __restrict__ lnb_g, const _Float16* __restrict__ WT,
    _Float16* __restrict__ kout, _Float16* __restrict__ vTout) {
  __shared__ union {
    struct { _Float16 A[128][72]; _Float16 B0[128][72]; _Float16 B1[128][72]; } s;
    _Float16 C[128][136];
  } u;
  __shared__ float s_mean[128], s_rstd[128], s_red[256][2], s_lnw[256], s_lnb[256];

  const int tid = threadIdx.x;
  const int bx = blockIdx.x;
  const size_t r0 = (size_t)bx * 128;
  const int w = tid >> 6, lane = tid & 63, quad = lane >> 4, l15 = lane & 15;

  s_lnw[tid] = lnw_g[tid];
  s_lnb[tid] = lnb_g[tid];
  {
    int row = tid >> 1, half = tid & 1;
    const float* p = x + (r0 + row) * 256 + half * 128;
    float s = 0.f, sq = 0.f;
    for (int i = 0; i < 32; i++) {
      float4 d = ((const float4*)p)[i];
      s += d.x + d.y + d.z + d.w;
      sq += d.x * d.x + d.y * d.y + d.z * d.z + d.w * d.w;
    }
    s_red[tid][0] = s; s_red[tid][1] = sq;
  }
  __syncthreads();
  if (tid < 128) {
    float s  = s_red[2 * tid][0] + s_red[2 * tid + 1][0];
    float sq = s_red[2 * tid][1] + s_red[2 * tid + 1][1];
    float m = s * (1.f / 256.f);
    float v = sq * (1.f / 256.f) - m * m;
    s_mean[tid] = m; s_rstd[tid] = rsqrtf(v + 1e-5f);
  }

  floatx4 acc0[2][8], acc1[2][8];
  for (int rt = 0; rt < 2; rt++)
    for (int ct = 0; ct < 8; ct++) {
      acc0[rt][ct] = (floatx4){0.f, 0.f, 0.f, 0.f};
      acc1[rt][ct] = (floatx4){0.f, 0.f, 0.f, 0.f};
    }

  for (int c = 0; c < 4; c++) {
    __syncthreads();
    for (int i = 0; i < 4; i++) {
      int g = tid + 256 * i;
      int row = g >> 3, c8 = g & 7;
      int col0 = c * 64 + c8 * 8;
      const float* p = x + (r0 + row) * 256 + col0;
      float4 d0 = ((const float4*)p)[0];
      float4 d1 = ((const float4*)p)[1];
      float f[8] = {d0.x, d0.y, d0.z, d0.w, d1.x, d1.y, d1.z, d1.w};
      float m = s_mean[row], rs = s_rstd[row];
      half8 hv;
      #pragma unroll
      for (int j = 0; j < 8; j++)
        hv[j] = (_Float16)((f[j] - m) * rs * s_lnw[col0 + j] + s_lnb[col0 + j]);
      *(half8*)&u.s.A[row][c8 * 8] = hv;
      *(half8*)&u.s.B0[row][c8 * 8] = *(const half8*)(WT + (size_t)row * 256 + col0);
      *(half8*)&u.s.B1[row][c8 * 8] = *(const half8*)(WT + (size_t)(128 + row) * 256 + col0);
    }
    __syncthreads();
    #pragma unroll
    for (int ks = 0; ks < 2; ks++) {
      half8 af0 = *(const half8*)&u.s.A[(2 * w) * 16 + l15][ks * 32 + quad * 8];
      half8 af1 = *(const half8*)&u.s.A[(2 * w + 1) * 16 + l15][ks * 32 + quad * 8];
      #pragma unroll
      for (int ct = 0; ct < 8; ct++) {
        half8 b0 = *(const half8*)&u.s.B0[ct * 16 + l15][ks * 32 + quad * 8];
        acc0[0][ct] = MFMA_F16(af0, b0, acc0[0][ct]);
        acc0[1][ct] = MFMA_F16(af1, b0, acc0[1][ct]);
        half8 b1 = *(const half8*)&u.s.B1[ct * 16 + l15][ks * 32 + quad * 8];
        acc1[0][ct] = MFMA_F16(af0, b1, acc1[0][ct]);
        acc1[1][ct] = MFMA_F16(af1, b1, acc1[1][ct]);
      }
    }
  }

  const size_t bt = (size_t)(bx >> 3);
  const int n0loc = (bx & 7) * 128;
  // k~ epilogue: direct coalesced stores
  for (int rt = 0; rt < 2; rt++)
    for (int ct = 0; ct < 8; ct++)
      #pragma unroll
      for (int r = 0; r < 4; r++) {
        size_t row = r0 + (2 * w + rt) * 16 + quad * 4 + r;
        kout[row * 128 + ct * 16 + l15] = (_Float16)acc0[rt][ct][r];
      }
  // v epilogue: transpose via LDS (C union reuses A/B space)
  __syncthreads();
  for (int rt = 0; rt < 2; rt++)
    for (int ct = 0; ct < 8; ct++)
      #pragma unroll
      for (int r = 0; r < 4; r++)
        u.C[(2 * w + rt) * 16 + quad * 4 + r][ct * 16 + l15] = (_Float16)acc1[rt][ct][r];
  __syncthreads();
  {
    int s = tid >> 1, hf = tid & 1;
    for (int j = 0; j < 8; j++) {
      int nb = hf * 64 + j * 8;
      half8 tmp;
      #pragma unroll
      for (int e = 0; e < 8; e++) tmp[e] = u.C[nb + e][s];
      *(half8*)(vTout + (bt * 128 + s) * 1024 + n0loc + nb) = tmp;
    }
  }
}

// ---------------------------------------------------------------------------
// phase 2: slot-attention scan. grid 128 (= 16 batches x 8 n-groups), 1024 thr.
// VERBATIM R5 (verified 810us): padded ctr/col_p; k~ fold (no q GEMM); vsum
// prologue per t; gh on waves 8-15 in ph2/ph3; 8-wave softmax; gi two-tile;
// gates+LN fused; fused predictor mha.
// ---------------------------------------------------------------------------
struct P2Args {
  const _Float16 *kbuf, *vT;
  const _Float16 *Wih, *Whh, *W1T, *W2T;
  const _Float16 *pQT, *pKT, *pVT, *pOT, *pF1T, *pF2T;
  const float *noise, *mu, *lsig;
  const float *lnsw, *lnsb, *lnmw, *lnmb;
  const float *bih, *bhh, *mb1, *mb2;
  const float *pl1w, *pl1b, *pl2w, *pl2b, *fb1, *fb2, *plfw, *plfb;
  float *out_slots, *out_attn;
  float *upd_p;   // [2][16][8][8*128]
  float *col_p;   // [2][16][8][64]  (8 used, 256B padded)
  float *vs_p;    // [16][8][128]
  int   *ctr;     // [16][64]        (1 used, 256B padded)
};

struct SH {
  _Float16 k_lds[128][136];   // k~ slice [n_local][s]
  _Float16 v_lds[128][136];   // v slice [s][n_local]
  float slots[8][128];
  _Float16 a16[16][136];
  _Float16 h16[16][136];
  float gi[8][384];
  float gh[8][384];
  union {
    struct { _Float16 attnT[16][136]; } sa;
    struct { _Float16 m16[16][264]; } mlp;
    struct { float qh[8][128]; float kh[8][128]; float vh[8][128]; float sc[4][8][8]; } mha;
    struct { _Float16 f16[16][520]; } ffn;
  } u;
  float colsum[8];
  float vsum[128];
  float bih[384], bhh[384], mb1[256], mb2[128], fb1[512], fb2[128];
  float lnsw[128], lnsb[128], lnmw[128], lnmb[128];
  float pl1w[128], pl1b[128], pl2w[128], pl2b[128], plfw[128], plfb[128];
};

__device__ __forceinline__ void group_barrier(int* ctr, int target) {
  __syncthreads();   // drains vmcnt: all agent-scope stores complete
  if (threadIdx.x == 0) {
    __hip_atomic_fetch_add(ctr, 1, __ATOMIC_ACQ_REL, __HIP_MEMORY_SCOPE_AGENT);
    while (__hip_atomic_load(ctr, __ATOMIC_ACQUIRE, __HIP_MEMORY_SCOPE_AGENT) < target)
      __builtin_amdgcn_s_sleep(1);
  }
  __syncthreads();
}

__device__ __forceinline__ void ln_to_a16(SH* sh, const float (*src)[128],
                                          const float* wv, const float* bv,
                                          int w, int lane) {
  if (w < 8) {
    float x0 = src[w][lane], x1 = src[w][lane + 64];
    float s = x0 + x1, sq = x0 * x0 + x1 * x1;
    #pragma unroll
    for (int m = 1; m < 64; m <<= 1) { s += __shfl_xor(s, m); sq += __shfl_xor(sq, m); }
    float mn = s * 0.0078125f;
    float vr = sq * 0.0078125f - mn * mn;
    float rs = rsqrtf(vr + 1e-5f);
    sh->a16[w][lane]      = (_Float16)((x0 - mn) * rs * wv[lane]      + bv[lane]);
    sh->a16[w][lane + 64] = (_Float16)((x1 - mn) * rs * wv[lane + 64] + bv[lane + 64]);
  } else {
    sh->a16[w][lane] = (_Float16)0.f;
    sh->a16[w][lane + 64] = (_Float16)0.f;
  }
}

__global__ __launch_bounds__(1024, 4) void slot_attn_kernel(P2Args P) {
  __shared__ SH sh;
  const int tid = threadIdx.x;
  const int w = tid >> 6, lane = tid & 63, quad = lane >> 4, l15 = lane & 15;
  const int b = blockIdx.x & 15;       // batch
  const int g = blockIdx.x >> 4;       // n-group (0..7)
  const int n0 = g * 128;
  int* ctrb = P.ctr + b * 64;          // 256B-padded counter
  int bar_phase = 0;

  for (int i = tid; i < 384; i += 1024) { sh.bih[i] = P.bih[i]; sh.bhh[i] = P.bhh[i]; }
  for (int i = tid; i < 256; i += 1024) sh.mb1[i] = P.mb1[i];
  for (int i = tid; i < 512; i += 1024) sh.fb1[i] = P.fb1[i];
  if (tid < 128) {
    sh.mb2[tid]  = P.mb2[tid];  sh.fb2[tid]  = P.fb2[tid];
    sh.lnsw[tid] = P.lnsw[tid]; sh.lnsb[tid] = P.lnsb[tid];
    sh.lnmw[tid] = P.lnmw[tid]; sh.lnmb[tid] = P.lnmb[tid];
    sh.pl1w[tid] = P.pl1w[tid]; sh.pl1b[tid] = P.pl1b[tid];
    sh.pl2w[tid] = P.pl2w[tid]; sh.pl2b[tid] = P.pl2b[tid];
    sh.plfw[tid] = P.plfw[tid]; sh.plfb[tid] = P.plfb[tid];
  }
  {
    int kk = tid >> 7, s = tid & 127;
    sh.slots[kk][s] = P.mu[s] + expf(P.lsig[s]) * P.noise[(b * 8 + kk) * 128 + s];
  }
  __syncthreads();

  for (int t = 0; t < 12; t++) {
    const _Float16* kt = P.kbuf + ((size_t)(b * 12 + t)) * 1024 * 128 + (size_t)n0 * 128;
    const _Float16* vt = P.vT   + ((size_t)(b * 12 + t)) * 128 * 1024 + n0;
    // ---- stage k~/v slice into LDS (32 KB each)
    {
      int r = tid >> 4, c8 = (tid & 15) * 8;
      #pragma unroll
      for (int p = 0; p < 2; p++) {
        int row = p * 64 + r;
        *(half8*)&sh.k_lds[row][c8] = *(const half8*)(kt + (size_t)row * 128 + c8);
        *(half8*)&sh.v_lds[row][c8] = *(const half8*)(vt + (size_t)row * 1024 + c8);
      }
    }
    if (tid < 128) sh.vsum[tid] = 0.f;
    __syncthreads();
    // ---- vsum partial over local n from v_lds
    {
      int s = tid >> 3, j = tid & 7;
      float a = 0.f;
      #pragma unroll
      for (int e = 0; e < 16; e++) a += (float)sh.v_lds[s][j * 16 + e];
      atomicAdd(&sh.vsum[s], a);
    }
    __syncthreads();
    if (tid < 128)
      __hip_atomic_store(&P.vs_p[(b * 8 + g) * 128 + tid], sh.vsum[tid],
                         __ATOMIC_RELAXED, __HIP_MEMORY_SCOPE_AGENT);

    for (int it = 0; it < 3; it++) {
      const int par = (t * 3 + it) & 1;
      float* updg = P.upd_p + ((size_t)(par * 16 + b) * 8 + g) * 1024;
      float* colg = P.col_p + ((size_t)(par * 16 + b) * 8 + g) * 64;
      // ---- ph1: LN(slots) -> a16 rows 0..7 (rows 8..15 zero); h16 = f16(slots)
      if (w < 8) {
        float x0 = sh.slots[w][lane], x1 = sh.slots[w][lane + 64];
        sh.h16[w][lane] = (_Float16)x0; sh.h16[w][lane + 64] = (_Float16)x1;
        float s = x0 + x1, sq = x0 * x0 + x1 * x1;
        #pragma unroll
        for (int m = 1; m < 64; m <<= 1) { s += __shfl_xor(s, m); sq += __shfl_xor(sq, m); }
        float mn = s * 0.0078125f;
        float vr = sq * 0.0078125f - mn * mn;
        float rs = rsqrtf(vr + 1e-5f);
        sh.a16[w][lane]      = (_Float16)((x0 - mn) * rs * sh.lnsw[lane]      + sh.lnsb[lane]);
        sh.a16[w][lane + 64] = (_Float16)((x1 - mn) * rs * sh.lnsw[lane + 64] + sh.lnsb[lane + 64]);
      } else {
        sh.h16[w][lane] = (_Float16)0.f; sh.h16[w][lane + 64] = (_Float16)0.f;
        sh.a16[w][lane] = (_Float16)0.f; sh.a16[w][lane + 64] = (_Float16)0.f;
      }
      if (tid < 8) sh.colsum[tid] = 0.f;
      __syncthreads();
      // ---- ph2: w<8: logits = k~ @ y^T, softmax, colsum; w>=8: gh tiles 0,1
      if (w < 8) {
        int nloc0 = w * 16;
        floatx4 acc = (floatx4){0.f, 0.f, 0.f, 0.f};
        const _Float16* ar = &sh.k_lds[nloc0 + l15][quad * 8];
        const _Float16* br = &sh.a16[l15][quad * 8];
        #pragma unroll
        for (int ks = 0; ks < 4; ks++)
          acc = MFMA_F16(*(const half8*)(ar + ks * 32), *(const half8*)(br + ks * 32), acc);
        float cs = 0.f;
        #pragma unroll
        for (int r = 0; r < 4; r++) {
          float v = (l15 < 8) ? acc[r] : -3.0e38f;
          float mx = v;
          mx = fmaxf(mx, __shfl_xor(mx, 1, 16));
          mx = fmaxf(mx, __shfl_xor(mx, 2, 16));
          mx = fmaxf(mx, __shfl_xor(mx, 4, 16));
          mx = fmaxf(mx, __shfl_xor(mx, 8, 16));
          float pv = (l15 < 8) ? expf(v - mx) : 0.f;
          float ss = pv;
          ss += __shfl_xor(ss, 1, 16); ss += __shfl_xor(ss, 2, 16);
          ss += __shfl_xor(ss, 4, 16); ss += __shfl_xor(ss, 8, 16);
          float pn = pv / ss;
          cs += pn;
          int nloc = nloc0 + quad * 4 + r;
          sh.u.sa.attnT[l15][nloc] = (_Float16)pn;
          if (it == 2 && l15 < 8)
            P.out_attn[((size_t)(b * 12 + t) * 1024 + n0 + nloc) * 8 + l15] = pn;
        }
        cs += __shfl_xor(cs, 16); cs += __shfl_xor(cs, 32);
        if (lane < 8) atomicAdd(&sh.colsum[lane], cs);
      } else {
        const int idx8 = w - 8;
        const _Float16* ar = &sh.h16[l15][quad * 8];
        #pragma unroll
        for (int tt = 0; tt < 2; tt++) {
          int ct = idx8 + tt * 8;
          const _Float16* Bg = P.Whh + (size_t)(ct * 16 + l15) * 128 + quad * 8;
          floatx4 acc = (floatx4){0.f, 0.f, 0.f, 0.f};
          #pragma unroll
          for (int ks = 0; ks < 4; ks++)
            acc = MFMA_F16(*(const half8*)(ar + ks * 32), *(const half8*)(Bg + ks * 32), acc);
          int col = ct * 16 + l15;
          #pragma unroll
          for (int r = 0; r < 4; r++) {
            int slot = quad * 4 + r;
            if (slot < 8) sh.gh[slot][col] = acc[r] + sh.bhh[col];
          }
        }
      }
      __syncthreads();
      // ---- ph3: w<8: partial updates = P^T @ v -> global; w>=8: gh tile 2
      if (w < 8) {
        floatx4 acc = (floatx4){0.f, 0.f, 0.f, 0.f};
        const _Float16* ar = &sh.u.sa.attnT[l15][quad * 8];
        const _Float16* br = &sh.v_lds[w * 16 + l15][quad * 8];
        #pragma unroll
        for (int ks = 0; ks < 4; ks++)
          acc = MFMA_F16(*(const half8*)(ar + ks * 32), *(const half8*)(br + ks * 32), acc);
        int scol = w * 16 + l15;
        #pragma unroll
        for (int r = 0; r < 4; r++) {
          int slot = quad * 4 + r;
          if (slot < 8)
            __hip_atomic_store(&updg[slot * 128 + scol], acc[r],
                               __ATOMIC_RELAXED, __HIP_MEMORY_SCOPE_AGENT);
        }
      } else {
        const int idx8 = w - 8;
        int ct = idx8 + 16;
        const _Float16* ar = &sh.h16[l15][quad * 8];
        const _Float16* Bg = P.Whh + (size_t)(ct * 16 + l15) * 128 + quad * 8;
        floatx4 acc = (floatx4){0.f, 0.f, 0.f, 0.f};
        #pragma unroll
        for (int ks = 0; ks < 4; ks++)
          acc = MFMA_F16(*(const half8*)(ar + ks * 32), *(const half8*)(Bg + ks * 32), acc);
        int col = ct * 16 + l15;
        #pragma unroll
        for (int r = 0; r < 4; r++) {
          int slot = quad * 4 + r;
          if (slot < 8) sh.gh[slot][col] = acc[r] + sh.bhh[col];
        }
      }
      if (tid < 8)
        __hip_atomic_store(&colg[tid], sh.colsum[tid],
                           __ATOMIC_RELAXED, __HIP_MEMORY_SCOPE_AGENT);
      // ---- 8-block barrier (padded counter)
      bar_phase++;
      group_barrier(ctrb, 8 * bar_phase);
      // ---- reduce partials (self-computed csum/vsum; no internal syncs)
      {
        int slot = tid >> 7, scol = tid & 127;
        const float* up = P.upd_p + (size_t)(par * 16 + b) * 8 * 1024 + slot * 128 + scol;
        float sum = 0.f;
        #pragma unroll
        for (int gg = 0; gg < 8; gg++)
          sum += __hip_atomic_load((float*)(up + gg * 1024),
                                   __ATOMIC_RELAXED, __HIP_MEMORY_SCOPE_AGENT);
        const float* cp = P.col_p + (size_t)(par * 16 + b) * 8 * 64 + slot;
        float csum = 0.f;
        #pragma unroll
        for (int gg = 0; gg < 8; gg++)
          csum += __hip_atomic_load((float*)(cp + gg * 64),
                                    __ATOMIC_RELAXED, __HIP_MEMORY_SCOPE_AGENT);
        float vsv;
        if (it == 0) {
          const float* vp = P.vs_p + b * 8 * 128 + scol;
          float vtot = 0.f;
          #pragma unroll
          for (int gg = 0; gg < 8; gg++)
            vtot += __hip_atomic_load((float*)(vp + gg * 128),
                                      __ATOMIC_RELAXED, __HIP_MEMORY_SCOPE_AGENT);
          if (slot == 0) sh.vsum[scol] = vtot;
          vsv = vtot;
        } else {
          vsv = sh.vsum[scol];
        }
        float upd = (sum + 1e-8f * vsv) / (csum + 1024.f * 1e-8f);
        sh.a16[slot][scol] = (_Float16)upd;
      }
      __syncthreads();
      // ---- GRU gi: all waves tile ct=w; w<8 also ct=16+w
      {
        const _Float16* ar = &sh.a16[l15][quad * 8];
        const _Float16* Bg = P.Wih + (size_t)(w * 16 + l15) * 128 + quad * 8;
        floatx4 acc = (floatx4){0.f, 0.f, 0.f, 0.f};
        #pragma unroll
        for (int ks = 0; ks < 4; ks++)
          acc = MFMA_F16(*(const half8*)(ar + ks * 32), *(const half8*)(Bg + ks * 32), acc);
        int col = w * 16 + l15;
        #pragma unroll
        for (int r = 0; r < 4; r++) {
          int slot = quad * 4 + r;
          if (slot < 8) sh.gi[slot][col] = acc[r] + sh.bih[col];
        }
        if (w < 8) {
          int col2 = (16 + w) * 16 + l15;
          const _Float16* Bg2 = P.Wih + (size_t)((16 + w) * 16 + l15) * 128 + quad * 8;
          floatx4 acc2 = (floatx4){0.f, 0.f, 0.f, 0.f};
          #pragma unroll
          for (int ks = 0; ks < 4; ks++)
            acc2 = MFMA_F16(*(const half8*)(ar + ks * 32), *(const half8*)(Bg2 + ks * 32), acc2);
          #pragma unroll
          for (int r = 0; r < 4; r++) {
            int slot = quad * 4 + r;
            if (slot < 8) sh.gi[slot][col2] = acc2[r] + sh.bih[col2];
          }
        }
      }
      __syncthreads();
      // ---- gates + LN fused (waves 0-7); writes slots + a16 (lnm / pl1)
      if (w < 8) {
        float h0 = sh.slots[w][lane], h1 = sh.slots[w][lane + 64];
        float r0 = 1.f / (1.f + expf(-(sh.gi[w][lane]       + sh.gh[w][lane])));
        float z0 = 1.f / (1.f + expf(-(sh.gi[w][128 + lane] + sh.gh[w][128 + lane])));
        float n0v = tanhf(sh.gi[w][256 + lane] + r0 * sh.gh[w][256 + lane]);
        float x0 = (1.f - z0) * n0v + z0 * h0;
        int l64 = lane + 64;
        float r1 = 1.f / (1.f + expf(-(sh.gi[w][l64]       + sh.gh[w][l64])));
        float z1 = 1.f / (1.f + expf(-(sh.gi[w][128 + l64] + sh.gh[w][128 + l64])));
        float n1v = tanhf(sh.gi[w][256 + l64] + r1 * sh.gh[w][256 + l64]);
        float x1 = (1.f - z1) * n1v + z1 * h1;
        sh.slots[w][lane] = x0; sh.slots[w][lane + 64] = x1;
        if (it == 2 && g == 0) {
          P.out_slots[((size_t)(b * 12 + t) * 8 + w) * 128 + lane]      = x0;
          P.out_slots[((size_t)(b * 12 + t) * 8 + w) * 128 + lane + 64] = x1;
        }
        const float* wv = (it < 2) ? sh.lnmw : sh.pl1w;
        const float* bv = (it < 2) ? sh.lnmb : sh.pl1b;
        float s = x0 + x1, sq = x0 * x0 + x1 * x1;
        #pragma unroll
        for (int m = 1; m < 64; m <<= 1) { s += __shfl_xor(s, m); sq += __shfl_xor(sq, m); }
        float mn = s * 0.0078125f;
        float vr = sq * 0.0078125f - mn * mn;
        float rs = rsqrtf(vr + 1e-5f);
        sh.a16[w][lane]      = (_Float16)((x0 - mn) * rs * wv[lane]      + bv[lane]);
        sh.a16[w][lane + 64] = (_Float16)((x1 - mn) * rs * wv[lane + 64] + bv[lane + 64]);
      }
      __syncthreads();
      // ---- residual MLP (iters 0,1)
      if (it < 2) {
        {
          floatx4 acc = (floatx4){0.f, 0.f, 0.f, 0.f};
          const _Float16* ar = &sh.a16[l15][quad * 8];
          const _Float16* br = P.W1T + (size_t)(w * 16 + l15) * 128 + quad * 8;
          #pragma unroll
          for (int ks = 0; ks < 4; ks++)
            acc = MFMA_F16(*(const half8*)(ar + ks * 32), *(const half8*)(br + ks * 32), acc);
          int col = w * 16 + l15;
          #pragma unroll
          for (int r = 0; r < 4; r++) {
            int slot = quad * 4 + r;
            if (slot < 8) sh.u.mlp.m16[slot][col] = (_Float16)fmaxf(acc[r] + sh.mb1[col], 0.f);
            else          sh.u.mlp.m16[slot][col] = (_Float16)0.f;
          }
        }
        __syncthreads();
        if (w < 8) {
          floatx4 acc = (floatx4){0.f, 0.f, 0.f, 0.f};
          const _Float16* ar = &sh.u.mlp.m16[l15][quad * 8];
          const _Float16* br = P.W2T + (size_t)(w * 16 + l15) * 256 + quad * 8;
          #pragma unroll
          for (int ks = 0; ks < 8; ks++)
            acc = MFMA_F16(*(const half8*)(ar + ks * 32), *(const half8*)(br + ks * 32), acc);
          int col = w * 16 + l15;
          #pragma unroll
          for (int r = 0; r < 4; r++) {
            int slot = quad * 4 + r;
            if (slot < 8) sh.slots[slot][col] += acc[r] + sh.mb2[col];
          }
        }
        __syncthreads();
      }
    } // it

    // ---- predictor (redundant, identical in all 8 blocks); a16 = LN_pl1
    {
      const _Float16* ar = &sh.a16[l15][quad * 8];
      int gg = w >> 3, ct = w & 7, col = ct * 16 + l15;
      const _Float16* Bg = (gg == 0 ? P.pQT : P.pKT) + (size_t)(ct * 16 + l15) * 128 + quad * 8;
      floatx4 acc = (floatx4){0.f, 0.f, 0.f, 0.f};
      #pragma unroll
      for (int ks = 0; ks < 4; ks++)
        acc = MFMA_F16(*(const half8*)(ar + ks * 32), *(const half8*)(Bg + ks * 32), acc);
      float scale = (gg == 0) ? 0.17677669529663687f : 1.f;
      float* dst = (gg == 0) ? &sh.u.mha.qh[0][0] : &sh.u.mha.kh[0][0];
      #pragma unroll
      for (int r = 0; r < 4; r++) {
        int slot = quad * 4 + r;
        if (slot < 8) dst[slot * 128 + col] = acc[r] * scale;
      }
      if (w < 8) {
        const _Float16* Bg2 = P.pVT + (size_t)(w * 16 + l15) * 128 + quad * 8;
        floatx4 a2 = (floatx4){0.f, 0.f, 0.f, 0.f};
        #pragma unroll
        for (int ks = 0; ks < 4; ks++)
          a2 = MFMA_F16(*(const half8*)(ar + ks * 32), *(const half8*)(Bg2 + ks * 32), a2);
        int colv = w * 16 + l15;
        #pragma unroll
        for (int r = 0; r < 4; r++) {
          int slot = quad * 4 + r;
          if (slot < 8) sh.u.mha.vh[slot][colv] = a2[r];
        }
      }
    }
    __syncthreads();
    // ---- fused mha: scores + softmax + P@V, one wave per head (w<4)
    if (w < 4) {
      int h = w, a = lane >> 3, b2 = lane & 7;
      const float* qr = &sh.u.mha.qh[a][h * 32];
      const float* kr = &sh.u.mha.kh[b2][h * 32];
      float s = 0.f;
      #pragma unroll
      for (int d = 0; d < 32; d++) s += qr[d] * kr[d];
      float mx = s;
      mx = fmaxf(mx, __shfl_xor(mx, 1, 8));
      mx = fmaxf(mx, __shfl_xor(mx, 2, 8));
      mx = fmaxf(mx, __shfl_xor(mx, 4, 8));
      float e = expf(s - mx);
      float ssum = e;
      ssum += __shfl_xor(ssum, 1, 8); ssum += __shfl_xor(ssum, 2, 8); ssum += __shfl_xor(ssum, 4, 8);
      float p = e / ssum;
      float o0 = 0.f, o1 = 0.f, o2 = 0.f, o3 = 0.f;
      int d0 = h * 32 + b2 * 4;
      #pragma unroll
      for (int j = 0; j < 8; j++) {
        float pj = __shfl(p, (a << 3) + j);
        const float* vr = &sh.u.mha.vh[j][d0];
        o0 += pj * vr[0]; o1 += pj * vr[1]; o2 += pj * vr[2]; o3 += pj * vr[3];
      }
      sh.a16[a][d0]     = (_Float16)o0;
      sh.a16[a][d0 + 1] = (_Float16)o1;
      sh.a16[a][d0 + 2] = (_Float16)o2;
      sh.a16[a][d0 + 3] = (_Float16)o3;
    }
    __syncthreads();
    if (w < 8) {       // s += o @ Wo
      floatx4 acc = (floatx4){0.f, 0.f, 0.f, 0.f};
      const _Float16* ar = &sh.a16[l15][quad * 8];
      const _Float16* br = P.pOT + (size_t)(w * 16 + l15) * 128 + quad * 8;
      #pragma unroll
      for (int ks = 0; ks < 4; ks++)
        acc = MFMA_F16(*(const half8*)(ar + ks * 32), *(const half8*)(br + ks * 32), acc);
      int col = w * 16 + l15;
      #pragma unroll
      for (int r = 0; r < 4; r++) {
        int slot = quad * 4 + r;
        if (slot < 8) sh.slots[slot][col] += acc[r];
      }
    }
    __syncthreads();
    ln_to_a16(&sh, sh.slots, sh.pl2w, sh.pl2b, w, lane);
    __syncthreads();
    for (int ct = w; ct < 32; ct += 16) {   // FFN1 + relu
      floatx4 acc = (floatx4){0.f, 0.f, 0.f, 0.f};
      const _Float16* ar = &sh.a16[l15][quad * 8];
      const _Float16* br = P.pF1T + (size_t)(ct * 16 + l15) * 128 + quad * 8;
      #pragma unroll
      for (int ks = 0; ks < 4; ks++)
        acc = MFMA_F16(*(const half8*)(ar + ks * 32), *(const half8*)(br + ks * 32), acc);
      int col = ct * 16 + l15;
      #pragma unroll
      for (int r = 0; r < 4; r++) {
        int slot = quad * 4 + r;
        if (slot < 8) sh.u.ffn.f16[slot][col] = (_Float16)fmaxf(acc[r] + sh.fb1[col], 0.f);
        else          sh.u.ffn.f16[slot][col] = (_Float16)0.f;
      }
    }
    __syncthreads();
    if (w < 8) {       // FFN2 + residual
      floatx4 acc = (floatx4){0.f, 0.f, 0.f, 0.f};
      const _Float16* ar = &sh.u.ffn.f16[l15][quad * 8];
      const _Float16* br = P.pF2T + (size_t)(w * 16 + l15) * 512 + quad * 8;
      #pragma unroll 4
      for (int ks = 0; ks < 16; ks++)
        acc = MFMA_F16(*(const half8*)(ar + ks * 32), *(const half8*)(br + ks * 32), acc);
      int col = w * 16 + l15;
      #pragma unroll
      for (int r = 0; r < 4; r++) {
        int slot = quad * 4 + r;
        if (slot < 8) sh.slots[slot][col] += acc[r] + sh.fb2[col];
      }
    }
    __syncthreads();
    if (w < 8) {       // final LN -> carry
      float x0 = sh.slots[w][lane], x1 = sh.slots[w][lane + 64];
      float s = x0 + x1, sq = x0 * x0 + x1 * x1;
      #pragma unroll
      for (int m = 1; m < 64; m <<= 1) { s += __shfl_xor(s, m); sq += __shfl_xor(sq, m); }
      float mn = s * 0.0078125f;
      float vr = sq * 0.0078125f - mn * mn;
      float rs = rsqrtf(vr + 1e-5f);
      sh.slots[w][lane]      = (x0 - mn) * rs * sh.plfw[lane]      + sh.plfb[lane];
      sh.slots[w][lane + 64] = (x1 - mn) * rs * sh.plfw[lane + 64] + sh.plfb[lane + 64];
    }
    __syncthreads();
  } // t
}

// ---------------------------------------------------------------------------
extern "C" void kernel_launch(void* const* d_in, const int* in_sizes, int n_in,
                              void* d_out, int out_size, void* d_ws, size_t ws_size,
                              hipStream_t stream) {
  const float* inp   = (const float*)d_in[0];
  const float* noise = (const float*)d_in[1];
  const float* mu    = (const float*)d_in[2];
  const float* lsig  = (const float*)d_in[3];
  const float* lniw  = (const float*)d_in[4];
  const float* lnib  = (const float*)d_in[5];
  const float* lnsw  = (const float*)d_in[6];
  const float* lnsb  = (const float*)d_in[7];
  const float* lnmw  = (const float*)d_in[8];
  const float* lnmb  = (const float*)d_in[9];
  const float* Wq    = (const float*)d_in[10];
  const float* Wk    = (const float*)d_in[11];
  const float* Wv    = (const float*)d_in[12];
  const float* gWih  = (const float*)d_in[13];
  const float* gWhh  = (const float*)d_in[14];
  const float* gbih  = (const float*)d_in[15];
  const float* gbhh  = (const float*)d_in[16];
  const float* mW1   = (const float*)d_in[17];
  const float* mb1   = (const float*)d_in[18];
  const float* mW2   = (const float*)d_in[19];
  const float* mb2   = (const float*)d_in[20];
  const float* pl1w  = (const float*)d_in[21];
  const float* pl1b  = (const float*)d_in[22];
  const float* pWq   = (const float*)d_in[23];
  const float* pWk   = (const float*)d_in[24];
  const float* pWv   = (const float*)d_in[25];
  const float* pWo   = (const float*)d_in[26];
  const float* pl2w  = (const float*)d_in[27];
  const float* pl2b  = (const float*)d_in[28];
  const float* pf1   = (const float*)d_in[29];
  const float* pfb1  = (const float*)d_in[30];
  const float* pf2   = (const float*)d_in[31];
  const float* pfb2  = (const float*)d_in[32];
  const float* plfw  = (const float*)d_in[33];
  const float* plfb  = (const float*)d_in[34];

  // workspace layout (f16 elements)
  _Float16* p   = (_Float16*)d_ws;
  _Float16* kbuf = p;  p += 25165824;
  _Float16* vT   = p;  p += 25165824;
  _Float16* WT   = p;  p += 65536;
  _Float16* Wih  = p;  p += 49152;
  _Float16* Whh  = p;  p += 49152;
  _Float16* W1T  = p;  p += 32768;
  _Float16* W2T  = p;  p += 32768;
  _Float16* pQT  = p;  p += 16384;
  _Float16* pKT  = p;  p += 16384;
  _Float16* pVT  = p;  p += 16384;
  _Float16* pOT  = p;  p += 16384;
  _Float16* pF1T = p;  p += 65536;
  _Float16* pF2T = p;  p += 65536;
  float* fb   = (float*)p;
  float* upd_p = fb;  fb += 2 * 16 * 8 * 1024;   // 262144
  float* col_p = fb;  fb += 2 * 16 * 8 * 64;     // 16384 (256B-padded groups)
  float* vs_p  = fb;  fb += 16 * 8 * 128;        // 16384
  int*   ctr   = (int*)fb;                       // 16 x 64 (256B-padded)

  const float kscale = 0.08838834764831845f;  // S^-0.5, S=128
  init_ctr_kernel<<<1, 1024, 0, stream>>>(ctr);

  PrepJobs J;
  const float* srcs[11] = {Wv, gWih, gWhh, mW1, mW2, pWq, pWk, pWv, pWo, pf1, pf2};
  _Float16* dsts[11]    = {WT + 32768, Wih, Whh, W1T, W2T, pQT, pKT, pVT, pOT, pF1T, pF2T};
  int Ins[11]    = {256, 49152, 49152, 128, 256, 128, 128, 128, 128, 128, 512};
  int Outs[11]   = {128, 1, 1, 256, 128, 128, 128, 128, 128, 512, 128};
  int elemss[11] = {32768, 49152, 49152, 32768, 32768, 16384, 16384, 16384, 16384, 65536, 65536};
  int doTs[11]   = {1, 0, 0, 1, 1, 1, 1, 1, 1, 1, 1};
  float scales[11] = {1.f, 1.f, 1.f, 1.f, 1.f, 1.f, 1.f, 1.f, 1.f, 1.f, 1.f};
  for (int j = 0; j < 11; j++) {
    J.src[j] = srcs[j]; J.dst[j] = dsts[j]; J.In[j] = Ins[j]; J.Out[j] = Outs[j];
    J.elems[j] = elemss[j]; J.doT[j] = doTs[j]; J.scale[j] = scales[j];
  }
  dim3 gp(256, 11, 1);
  prep_all_kernel<<<gp, 256, 0, stream>>>(J);
  prep_wtilde_kernel<<<128, 256, 0, stream>>>(Wk, Wq, WT, kscale);

  gemm_kv_kernel<<<1536, 256, 0, stream>>>(inp, lniw, lnib, WT, kbuf, vT);

  P2Args a;
  a.kbuf = kbuf; a.vT = vT;
  a.Wih = Wih; a.Whh = Whh; a.W1T = W1T; a.W2T = W2T;
  a.pQT = pQT; a.pKT = pKT; a.pVT = pVT; a.pOT = pOT; a.pF1T = pF1T; a.pF2T = pF2T;
  a.noise = noise; a.mu = mu; a.lsig = lsig;
  a.lnsw = lnsw; a.lnsb = lnsb; a.lnmw = lnmw; a.lnmb = lnmb;
  a.bih = gbih; a.bhh = gbhh; a.mb1 = mb1; a.mb2 = mb2;
  a.pl1w = pl1w; a.pl1b = pl1b; a.pl2w = pl2w; a.pl2b = pl2b;
  a.fb1 = pfb1; a.fb2 = pfb2; a.plfw = plfw; a.plfb = plfb;
  a.out_slots = (float*)d_out;
  a.out_attn  = (float*)d_out + 196608;
  a.upd_p = upd_p; a.col_p = col_p; a.vs_p = vs_p; a.ctr = ctr;

  slot_attn_kernel<<<128, 1024, 0, stream>>>(a);
}